// Round 5
// baseline (4387.970 us; speedup 1.0000x reference)
//
#include <hip/hip_runtime.h>
#include <hip/hip_bf16.h>
#include <hip/hip_fp16.h>
#include <cmath>

using bf16 = __hip_bfloat16;
typedef __attribute__((ext_vector_type(8))) short short8;
typedef __attribute__((ext_vector_type(4))) float floatx4;
typedef unsigned long long u64t;

__device__ __forceinline__ void lds_load16(void* lds, const void* g) {
  __builtin_amdgcn_global_load_lds(
      (const __attribute__((address_space(1))) void*)g,
      (__attribute__((address_space(3))) void*)lds, 16, 0, 0);
}

// ---------------- generic BT GEMM: C[M][N] = scale*(A[M][K] x B[N][K]^T) + bias ----------
struct GemmP {
  const bf16* A; const bf16* B;
  int M, N, K, lda, ldb;
  long sAimg, sAh, sBimg, sBh;
  int ZH, cross;
  float scale;
  const float* bias;
  float* Cf; int ldcf; long sCfImg, sCfH;
  bf16* Cb; int ldcb; long sCbImg, sCbH;
  __half* Ch; int ldch; long sChImg, sChH;
  const float* resid;  // fp32, same indexing as Cf
};

template <int NTILE>  // 128: 4 waves x (64x64); 64: 4 waves x (32x64)
__global__ __launch_bounds__(256, 2)
void gemm_bt(GemmP p) {
  __shared__ __align__(16) bf16 As[128 * 32];
  __shared__ __align__(16) bf16 Bs[NTILE * 32];
  constexpr int MI = (NTILE == 128) ? 4 : 2;
  const int z = blockIdx.z;
  const int imgA = z / p.ZH;
  const int h = z - imgA * p.ZH;
  const int imgB = imgA ^ p.cross;
  const bf16* Ab = p.A + (long)imgA * p.sAimg + (long)h * p.sAh;
  const bf16* Bb = p.B + (long)imgB * p.sBimg + (long)h * p.sBh;
  const int m0 = blockIdx.y * 128, n0 = blockIdx.x * NTILE;
  const int t = threadIdx.x, w = t >> 6, l = t & 63;
  const int lr = l >> 2, lk = (l & 3) * 8;   // staging: row-in-chunk, k-elem offset
  const int fr = l & 15, fk = (l >> 4) * 8;  // fragment: row-in-16tile, k offset

  const bf16* aG0 = Ab + (long)(m0 + w * 16 + lr) * p.lda + lk;
  const bf16* aG1 = aG0 + (long)64 * p.lda;
  const bf16* bG0 = Bb + (long)(n0 + w * 16 + lr) * p.ldb + lk;
  const bf16* bG1 = bG0 + (long)64 * p.ldb;
  bf16* aL0 = &As[w * 16 * 32];
  bf16* aL1 = &As[(w + 4) * 16 * 32];
  bf16* bL0 = &Bs[w * 16 * 32];
  bf16* bL1 = &Bs[(w + 4) * 16 * 32];
  const int wr = (NTILE == 128) ? (w >> 1) * 64 : w * 32;
  const int wc = (NTILE == 128) ? (w & 1) * 64 : 0;

  floatx4 zero4 = {0.f, 0.f, 0.f, 0.f};
  floatx4 acc[MI][4];
#pragma unroll
  for (int i = 0; i < MI; i++)
#pragma unroll
    for (int j = 0; j < 4; j++) acc[i][j] = zero4;

  for (int k0 = 0; k0 < p.K; k0 += 32) {
    lds_load16(aL0, aG0 + k0);
    lds_load16(aL1, aG1 + k0);
    lds_load16(bL0, bG0 + k0);
    if (NTILE == 128) lds_load16(bL1, bG1 + k0);
    __syncthreads();
    short8 af[MI], bfv[4];
#pragma unroll
    for (int i = 0; i < MI; i++)
      af[i] = *(const short8*)&As[(wr + i * 16 + fr) * 32 + fk];
#pragma unroll
    for (int j = 0; j < 4; j++)
      bfv[j] = *(const short8*)&Bs[(wc + j * 16 + fr) * 32 + fk];
#pragma unroll
    for (int i = 0; i < MI; i++)
#pragma unroll
      for (int j = 0; j < 4; j++)
        acc[i][j] = __builtin_amdgcn_mfma_f32_16x16x32_bf16(af[i], bfv[j], acc[i][j], 0, 0, 0);
    __syncthreads();
  }

  // epilogue: D[row][col], col = lane&15, row = (lane>>4)*4 + r  [m89-verified layout]
  const int cl = l & 15, rq = (l >> 4) * 4;
  const long cfBase = (long)imgA * p.sCfImg + (long)h * p.sCfH;
  const long cbBase = (long)imgA * p.sCbImg + (long)h * p.sCbH;
  const long chBase = (long)imgA * p.sChImg + (long)h * p.sChH;
#pragma unroll
  for (int j = 0; j < 4; j++) {
    const int col = n0 + wc + j * 16 + cl;
    if (col >= p.N) continue;
    const float bv = p.bias ? p.bias[col] : 0.f;
#pragma unroll
    for (int i = 0; i < MI; i++) {
#pragma unroll
      for (int r = 0; r < 4; r++) {
        const int row = m0 + wr + i * 16 + rq + r;
        float val = acc[i][j][r] * p.scale + bv;
        if (p.resid) val += p.resid[cfBase + (long)row * p.ldcf + col];
        if (p.Cf) p.Cf[cfBase + (long)row * p.ldcf + col] = val;
        if (p.Cb) p.Cb[cbBase + (long)row * p.ldcb + col] = __float2bfloat16(val);
        if (p.Ch) p.Ch[chBase + (long)row * p.ldch + col] = __float2half(val);
      }
    }
  }
}

// ---------------- fused flash attention (r3-verified) ----------------
// Writes directly into Yb[:, 512:1024] (the old msg slot): O in head-major channels,
// which matches the wm'-column space that the folded Wc was built in.
__global__ __launch_bounds__(256, 2)
void attn_fused(const bf16* __restrict__ QKV, const bf16* __restrict__ vchan,
                bf16* __restrict__ Yb, int cross) {
  __shared__ __align__(16) bf16 Qs[128 * 64];
  __shared__ __align__(16) bf16 Ks[64 * 64];
  __shared__ __align__(16) bf16 Vs[64 * 64];
  __shared__ __align__(16) bf16 Ps[128 * 64];
  const int z = blockIdx.z;
  const int img = z >> 3, h = z & 7;
  const int imgB = img ^ cross;
  const int q0 = blockIdx.x * 128;
  const int t = threadIdx.x, w = t >> 6, l = t & 63;
  const int g = l >> 4, fr = l & 15;
  const int wr = w * 32;

  {
    const bf16* src = QKV + ((long)(img * 1024 + q0)) * 1536 + h * 64;
#pragma unroll
    for (int k = 0; k < 4; k++) {
      const int chunk = t + k * 256;
      const int row = chunk >> 3, c16 = chunk & 7;
      const short8 vd = *(const short8*)(src + (long)row * 1536 + c16 * 8);
      *(short8*)((char*)Qs + row * 128 + ((c16 * 16) ^ ((row & 7) << 4))) = vd;
    }
  }
  __syncthreads();

  short8 qf[2][2];
#pragma unroll
  for (int i = 0; i < 2; i++)
#pragma unroll
    for (int ks = 0; ks < 2; ks++) {
      const int row = wr + i * 16 + fr;
      qf[i][ks] = *(const short8*)((const char*)Qs + row * 128 +
                                   ((ks * 64 + g * 16) ^ ((row & 7) << 4)));
    }

  floatx4 zero4 = {0.f, 0.f, 0.f, 0.f};
  floatx4 Oa[2][4];
  float m_run[2][4], l_run[2][4];
#pragma unroll
  for (int i = 0; i < 2; i++)
#pragma unroll
    for (int r = 0; r < 4; r++) { m_run[i][r] = -3.0e38f; l_run[i][r] = 0.f; }
#pragma unroll
  for (int i = 0; i < 2; i++)
#pragma unroll
    for (int jd = 0; jd < 4; jd++) Oa[i][jd] = zero4;

  const bf16* ksrc0 = QKV + ((long)(imgB * 1024)) * 1536 + 512 + h * 64;
  const bf16* vsrc0 = vchan + (long)imgB * 524288 + (long)(h * 64) * 1024;

  for (int kv = 0; kv < 16; kv++) {
    const int kv0 = kv * 64;
#pragma unroll
    for (int k = 0; k < 2; k++) {
      const int ch = t + k * 256;
      const int row = ch >> 3, c16 = ch & 7;
      const short8 vd = *(const short8*)(ksrc0 + (long)(kv0 + row) * 1536 + c16 * 8);
      *(short8*)((char*)Ks + row * 128 + ((c16 * 16) ^ ((row & 7) << 4))) = vd;
    }
#pragma unroll
    for (int k = 0; k < 2; k++) {
      const int ch = t + k * 256;
      const int row = ch >> 3, c16 = ch & 7;
      const short8 vd = *(const short8*)(vsrc0 + (long)row * 1024 + kv0 + c16 * 8);
      *(short8*)((char*)Vs + row * 128 + ((c16 * 16) ^ ((row & 7) << 4))) = vd;
    }
    __syncthreads();

    floatx4 sa[2][4];
#pragma unroll
    for (int i = 0; i < 2; i++)
#pragma unroll
      for (int j = 0; j < 4; j++) sa[i][j] = zero4;
    short8 bk[4][2];
#pragma unroll
    for (int j = 0; j < 4; j++)
#pragma unroll
      for (int ks = 0; ks < 2; ks++) {
        const int row = j * 16 + fr;
        bk[j][ks] = *(const short8*)((const char*)Ks + row * 128 +
                                     ((ks * 64 + g * 16) ^ ((row & 7) << 4)));
      }
#pragma unroll
    for (int i = 0; i < 2; i++)
#pragma unroll
      for (int j = 0; j < 4; j++)
#pragma unroll
        for (int ks = 0; ks < 2; ks++)
          sa[i][j] = __builtin_amdgcn_mfma_f32_16x16x32_bf16(qf[i][ks], bk[j][ks], sa[i][j], 0, 0, 0);

#pragma unroll
    for (int i = 0; i < 2; i++) {
#pragma unroll
      for (int r = 0; r < 4; r++) {
        float mx = -3.0e38f;
#pragma unroll
        for (int j = 0; j < 4; j++) {
          sa[i][j][r] *= 0.125f;
          mx = fmaxf(mx, sa[i][j][r]);
        }
#pragma unroll
        for (int o = 1; o < 16; o <<= 1) mx = fmaxf(mx, __shfl_xor(mx, o));
        const float mnew = fmaxf(m_run[i][r], mx);
        const float corr = __expf(m_run[i][r] - mnew);
        m_run[i][r] = mnew;
        float ps = 0.f;
#pragma unroll
        for (int j = 0; j < 4; j++) {
          const float pv = __expf(sa[i][j][r] - mnew);
          sa[i][j][r] = pv;
          ps += pv;
        }
#pragma unroll
        for (int o = 1; o < 16; o <<= 1) ps += __shfl_xor(ps, o);
        l_run[i][r] = l_run[i][r] * corr + ps;
#pragma unroll
        for (int jd = 0; jd < 4; jd++) Oa[i][jd][r] *= corr;
      }
    }

#pragma unroll
    for (int i = 0; i < 2; i++)
#pragma unroll
      for (int j = 0; j < 4; j++)
#pragma unroll
        for (int r = 0; r < 4; r++) {
          const int row = wr + i * 16 + g * 4 + r;
          const int colB = j * 32 + fr * 2;
          *(bf16*)((char*)Ps + row * 128 + (colB ^ ((row & 7) << 4))) =
              __float2bfloat16(sa[i][j][r]);
        }

    short8 pf[2][2], vf[4][2];
#pragma unroll
    for (int i = 0; i < 2; i++)
#pragma unroll
      for (int ks = 0; ks < 2; ks++) {
        const int row = wr + i * 16 + fr;
        pf[i][ks] = *(const short8*)((const char*)Ps + row * 128 +
                                     ((ks * 64 + g * 16) ^ ((row & 7) << 4)));
      }
#pragma unroll
    for (int jd = 0; jd < 4; jd++)
#pragma unroll
      for (int ks = 0; ks < 2; ks++) {
        const int row = jd * 16 + fr;
        vf[jd][ks] = *(const short8*)((const char*)Vs + row * 128 +
                                      ((ks * 64 + g * 16) ^ ((row & 7) << 4)));
      }
#pragma unroll
    for (int i = 0; i < 2; i++)
#pragma unroll
      for (int jd = 0; jd < 4; jd++)
#pragma unroll
        for (int ks = 0; ks < 2; ks++)
          Oa[i][jd] = __builtin_amdgcn_mfma_f32_16x16x32_bf16(pf[i][ks], vf[jd][ks], Oa[i][jd], 0, 0, 0);
    __syncthreads();
  }

  // epilogue: O /= l, write Yb[img][token][512 + h*64 + d]
#pragma unroll
  for (int i = 0; i < 2; i++) {
#pragma unroll
    for (int r = 0; r < 4; r++) {
      const float inv = 1.f / l_run[i][r];
      const int qrow = q0 + wr + i * 16 + g * 4 + r;
      bf16* dst = Yb + ((long)img * 1024 + qrow) * 1024 + 512 + h * 64;
#pragma unroll
      for (int jd = 0; jd < 4; jd++)
        dst[jd * 16 + fr] = __float2bfloat16(Oa[i][jd][r] * inv);
    }
  }
}

// ---------------- elementwise / helper kernels ----------------
__global__ __launch_bounds__(256)
void cvt_f2b(const float* __restrict__ in, bf16* __restrict__ out, long n) {
  long i = (long)blockIdx.x * 256 + threadIdx.x;
  const long stride = (long)gridDim.x * 256;
  for (; i < n; i += stride) out[i] = __float2bfloat16(in[i]);
}

// upfront: bf16 conversions for the Wm->W1 fold.
// w1r[12][1024][512] = W1[:, :, 512:]; wmT[12][512 c][512 i] = Wm[l][i][perm(c)]
__global__ __launch_bounds__(256)
void cvt_prep(const float* __restrict__ W1, const float* __restrict__ Wm,
              bf16* __restrict__ w1r, bf16* __restrict__ wmT) {
  const long i = (long)blockIdx.x * 256 + threadIdx.x;
  if (i < 6291456L) {
    const int lay = (int)(i >> 19);
    const long r = i & 524287;
    const int o = (int)(r >> 9), k = (int)(r & 511);
    w1r[i] = __float2bfloat16(W1[(long)lay * 1048576 + (long)o * 1024 + 512 + k]);
  } else if (i < 9437184L) {
    const long j = i - 6291456L;
    const int lay = (int)(j >> 18);
    const long r = j & 262143;
    const int c = (int)(r >> 9), ii = (int)(r & 511);
    wmT[j] = __float2bfloat16(Wm[(long)lay * 262144 + (long)ii * 512 + (c & 63) * 8 + (c >> 6)]);
  }
}

// upfront: bc[l][o] = b1[l][o] + sum_i W1[l][o][512+i]*bm[l][i]  (wave per output)
__global__ __launch_bounds__(256)
void bc_calc(const float* __restrict__ W1, const float* __restrict__ bm,
             const float* __restrict__ b1, float* __restrict__ bc) {
  const int w = threadIdx.x >> 6, l = threadIdx.x & 63;
  const int og = blockIdx.x * 4 + w;  // 0..12287
  const int lay = og >> 10, o = og & 1023;
  const float* wrow = W1 + (long)lay * 1048576 + (long)o * 1024 + 512;
  const float* bmr = bm + lay * 512;
  float s = 0.f;
#pragma unroll
  for (int j = 0; j < 8; j++) s += wrow[l + 64 * j] * bmr[l + 64 * j];
#pragma unroll
  for (int o2 = 32; o2 >= 1; o2 >>= 1) s += __shfl_xor(s, o2);
  if (l == 0) bc[og] = b1[og] + s;
}

// per-layer weight conversion (4.5 MB rotating):
// [0:768K) wqkv | [768K:1.75M) w1merged = [W1left | Wc] | [1.75M:2.25M) w2
__global__ __launch_bounds__(256)
void cvt_layer(const float* __restrict__ Wq, const float* __restrict__ Wk,
               const float* __restrict__ Wv, const float* __restrict__ W1,
               const float* __restrict__ W2, const bf16* __restrict__ wcAll,
               const float* __restrict__ bq, const float* __restrict__ bk,
               const float* __restrict__ bv,
               int layer, bf16* __restrict__ out, float* __restrict__ bqkv) {
  const long i = (long)blockIdx.x * 256 + threadIdx.x;
  if (i >= 2359296L + 1536) return;
  if (i >= 2359296L) {
    const int j = (int)(i - 2359296L);
    float b;
    if (j < 512) b = bq[layer * 512 + j];
    else if (j < 1024) b = bk[layer * 512 + j - 512];
    else b = bv[layer * 512 + j - 1024];
    bqkv[j] = b;
    return;
  }
  if (i < 786432) {
    float v;
    if (i < 262144) v = Wq[(long)layer * 262144 + i];
    else if (i < 524288) v = Wk[(long)layer * 262144 + i - 262144];
    else v = Wv[(long)layer * 262144 + i - 524288];
    out[i] = __float2bfloat16(v);
  } else if (i < 1835008) {
    const long j = i - 786432;
    const int o = (int)(j >> 10), k = (int)(j & 1023);
    if (k < 512)
      out[i] = __float2bfloat16(W1[(long)layer * 1048576 + (long)o * 1024 + k]);
    else
      out[i] = wcAll[(long)layer * 524288 + (long)o * 512 + (k - 512)];
  } else {
    const long j = i - 1835008;
    out[i] = __float2bfloat16(W2[(long)layer * 524288 + j]);
  }
}

__global__ __launch_bounds__(256)
void init_x(const float* __restrict__ d0, const float* __restrict__ d1,
            float* __restrict__ Xf, bf16* __restrict__ Yb) {
  long i = (long)blockIdx.x * 256 + threadIdx.x;
  const long stride = (long)gridDim.x * 256;
  const long n = 8L * 1024 * 512;
  for (; i < n; i += stride) {
    const int d = (int)(i & 511);
    const long nn = i >> 9;  // img*1024 + row
    const int img = (int)(nn >> 10);
    const int row = (int)(nn & 1023);
    const int b = img >> 1, s = img & 1;
    const float v = (s ? d1 : d0)[((long)b * 1024 + row) * 512 + d];
    Xf[i] = v;
    Yb[(nn << 10) + d] = __float2bfloat16(v);
  }
}

// transpose [8][1024][512-cols-of-ldi] (2-byte elems) -> [8][512][1024]
__global__ __launch_bounds__(256)
void transpose_2b(const unsigned short* __restrict__ in, int ldi,
                  unsigned short* __restrict__ out) {
  __shared__ unsigned short tile[64][65];
  const int img = blockIdx.z;
  const int m0 = blockIdx.y * 64, c0 = blockIdx.x * 64;
  const int col = threadIdx.x & 63, r0 = threadIdx.x >> 6;
  const unsigned short* ip = in + ((long)img * 1024 + m0) * ldi + c0;
#pragma unroll
  for (int i = 0; i < 16; i++) { int r = r0 + i * 4; tile[r][col] = ip[(long)r * ldi + col]; }
  __syncthreads();
  unsigned short* op = out + ((long)img * 512 + c0) * 1024 + m0;
#pragma unroll
  for (int i = 0; i < 16; i++) { int r = r0 + i * 4; op[(long)r * 1024 + col] = tile[col][r]; }
}

// fused instance-norm: one kernel does stats (atomics) + device-wide arrival +
// apply-from-registers. 1024 co-resident blocks (launch_bounds(256,4) caps VGPR at
// 128 -> >=4 blocks/CU -> capacity 1024). Saves a full 32MB T1 re-read + 2 launches.
__global__ __launch_bounds__(256, 4)
void in_norm(const float* __restrict__ T1, bf16* __restrict__ Z,
             float* __restrict__ stats, unsigned int* __restrict__ ctr) {
  const int t = threadIdx.x;
  float vals[2][16];
  float s[4] = {0.f, 0.f, 0.f, 0.f}, s2[4] = {0.f, 0.f, 0.f, 0.f};
  const long base0 = (long)blockIdx.x * 8192;
  const int img = (int)(base0 >> 20);  // 8192 | 1M -> both chunks in same img
#pragma unroll
  for (int ch = 0; ch < 2; ch++) {
    const long base = base0 + ch * 4096;
#pragma unroll
    for (int j = 0; j < 16; j++) {
      const float v = T1[base + t + j * 256];
      vals[ch][j] = v;
      s[j & 3] += v;
      s2[j & 3] += v * v;
    }
  }
#pragma unroll
  for (int k = 0; k < 4; k++) {
    const int c = (t + 256 * k) & 1023;
    atomicAdd(&stats[img * 2048 + c], s[k]);
    atomicAdd(&stats[img * 2048 + 1024 + c], s2[k]);
  }
  __syncthreads();  // drain this block's atomics (vmcnt) before arrival
  if (t == 0) {
    __hip_atomic_fetch_add(ctr, 1u, __ATOMIC_RELEASE, __HIP_MEMORY_SCOPE_AGENT);
    while (__hip_atomic_load(ctr, __ATOMIC_RELAXED, __HIP_MEMORY_SCOPE_AGENT) < 1024u)
      __builtin_amdgcn_s_sleep(2);
    (void)__hip_atomic_load(ctr, __ATOMIC_ACQUIRE, __HIP_MEMORY_SCOPE_AGENT);
  }
  __syncthreads();
  float mean[4], inv[4];
#pragma unroll
  for (int k = 0; k < 4; k++) {
    const int c = (t + 256 * k) & 1023;
    const float m = __hip_atomic_load(&stats[img * 2048 + c], __ATOMIC_RELAXED,
                                      __HIP_MEMORY_SCOPE_AGENT) * (1.f / 1024.f);
    const float q = __hip_atomic_load(&stats[img * 2048 + 1024 + c], __ATOMIC_RELAXED,
                                      __HIP_MEMORY_SCOPE_AGENT) * (1.f / 1024.f);
    const float vr = fmaxf(q - m * m, 0.f);
    mean[k] = m;
    inv[k] = rsqrtf(vr + 1e-5f);
  }
#pragma unroll
  for (int ch = 0; ch < 2; ch++) {
    const long base = base0 + ch * 4096;
#pragma unroll
    for (int j = 0; j < 16; j++) {
      const float z = (vals[ch][j] - mean[j & 3]) * inv[j & 3];
      Z[base + t + j * 256] = __float2bfloat16(fmaxf(z, 0.f));
    }
  }
}

// fp32 coupling -> fp16 copy + fp16 transpose, with bin rows/cols filled inline
__global__ __launch_bounds__(256)
void coup_to_fp16(float* __restrict__ io, const float* __restrict__ alpha,
                  __half* __restrict__ outN, __half* __restrict__ outT) {
  __shared__ float tile[32][33];
  const float a = *alpha;
  const int b = blockIdx.z;
  const int x0 = blockIdx.x * 32, y0 = blockIdx.y * 32;
  const int lx = threadIdx.x & 31, ly = threadIdx.x >> 5;  // ly 0..7
#pragma unroll
  for (int i = 0; i < 4; i++) {
    const int y = ly + i * 8;
    if (y0 + y < 1025 && x0 + lx < 1025) {
      const long idx = ((long)b * 1025 + y0 + y) * 1025 + x0 + lx;
      const bool edge = (y0 + y == 1024) || (x0 + lx == 1024);
      float vv;
      if (edge) { vv = a; io[idx] = a; }
      else vv = io[idx];
      tile[y][lx] = vv;
      outN[idx] = __float2half(vv);
    }
  }
  __syncthreads();
#pragma unroll
  for (int i = 0; i < 4; i++) {
    const int y = ly + i * 8;
    if (x0 + y < 1025 && y0 + lx < 1025)
      outT[((long)b * 1025 + x0 + y) * 1025 + y0 + lx] = __float2half(tile[lx][y]);
  }
}

// -------- persistent Sinkhorn (r9 structure: per-lane spin on tagged u64 entries) ----
#define SK_BLOCKS 256

#define SK_ROUND(CREG, CLAST, XREG, XLAST, SRC, DST)                            \
  {                                                                             \
    u64t pr;                                                                    \
    while ((unsigned)((pr = __hip_atomic_load(&(SRC)[t], __ATOMIC_RELAXED,      \
                                              __HIP_MEMORY_SCOPE_AGENT)) >>    \
                      32) != tag)                                               \
      __builtin_amdgcn_s_sleep(1);                                              \
    sv[t] = __uint_as_float((unsigned)pr);                                      \
    if (t == 0) {                                                               \
      u64t qr;                                                                  \
      while ((unsigned)((qr = __hip_atomic_load(&(SRC)[1024], __ATOMIC_RELAXED, \
                                                __HIP_MEMORY_SCOPE_AGENT)) >>  \
                        32) != tag)                                             \
        __builtin_amdgcn_s_sleep(1);                                            \
      sv[1024] = __uint_as_float((unsigned)qr);                                 \
    }                                                                           \
    __syncthreads();                                                            \
    float M = (l == 0) ? ((CLAST) + sv[1024]) : -3.0e38f;                       \
    const float extra = M;                                                      \
    float x[16];                                                                \
    _Pragma("unroll") for (int i = 0; i < 16; i++) {                            \
      x[i] = (CREG)[i] + sv[l + 64 * i];                                        \
      M = fmaxf(M, x[i]);                                                       \
    }                                                                           \
    _Pragma("unroll") for (int o = 32; o >= 1; o >>= 1)                         \
        M = fmaxf(M, __shfl_xor(M, o));                                         \
    float S = (l == 0) ? __expf(extra - M) : 0.f;                               \
    _Pragma("unroll") for (int i = 0; i < 16; i++) S += __expf(x[i] - M);       \
    _Pragma("unroll") for (int o = 32; o >= 1; o >>= 1) S += __shfl_xor(S, o);  \
    if (l == 0) {                                                               \
      const float val = norm - (M + __logf(S));                                 \
      const u64t pk = ((u64t)(tag + 1) << 32) | (u64t)__float_as_uint(val);     \
      __hip_atomic_store(&(DST)[lw], pk, __ATOMIC_RELAXED,                      \
                         __HIP_MEMORY_SCOPE_AGENT);                             \
    }                                                                           \
    if (xtra) {                                                                 \
      float M2 = (l == 0) ? ((XLAST) + sv[1024]) : -3.0e38f;                    \
      const float e2 = M2;                                                      \
      float y[16];                                                              \
      _Pragma("unroll") for (int i = 0; i < 16; i++) {                          \
        y[i] = (XREG)[i] + sv[l + 64 * i];                                      \
        M2 = fmaxf(M2, y[i]);                                                   \
      }                                                                         \
      _Pragma("unroll") for (int o = 32; o >= 1; o >>= 1)                       \
          M2 = fmaxf(M2, __shfl_xor(M2, o));                                    \
      float S2 = (l == 0) ? __expf(e2 - M2) : 0.f;                              \
      _Pragma("unroll") for (int i = 0; i < 16; i++) S2 += __expf(y[i] - M2);   \
      _Pragma("unroll") for (int o = 32; o >= 1; o >>= 1)                       \
          S2 += __shfl_xor(S2, o);                                              \
      if (l == 0) {                                                             \
        const float v2 = (logN + norm) - (M2 + __logf(S2));                     \
        const u64t pk2 = ((u64t)(tag + 1) << 32) | (u64t)__float_as_uint(v2);   \
        __hip_atomic_store(&(DST)[1024], pk2, __ATOMIC_RELAXED,                 \
                           __HIP_MEMORY_SCOPE_AGENT);                           \
      }                                                                         \
    }                                                                           \
    tag++;                                                                      \
    __syncthreads();                                                            \
  }

__global__ __launch_bounds__(1024)
void sinkhorn_pers(const __half* __restrict__ C, const __half* __restrict__ CT,
                   u64t* __restrict__ u, u64t* __restrict__ v,
                   float norm, float logN, int iters) {
  __shared__ float sv[1025];
  const int t = threadIdx.x;
  const int w = t >> 6, l = t & 63;
  const int b = blockIdx.x >> 6;   // batch 0..3
  const int kb = blockIdx.x & 63;  // block within batch
  const int lw = kb * 16 + w;      // wave's row within batch: 0..1023
  const __half* Cb = C + (long)b * 1050625;
  const __half* CTb = CT + (long)b * 1050625;
  u64t* ub = u + b * 1025;
  u64t* vb = v + b * 1025;

  float cr[16], cc[16];
  float clC, clT;
  {
    const __half* rc = Cb + (long)lw * 1025;
    const __half* rt = CTb + (long)lw * 1025;
#pragma unroll
    for (int i = 0; i < 16; i++) {
      cr[i] = __half2float(rc[l + 64 * i]);
      cc[i] = __half2float(rt[l + 64 * i]);
    }
    clC = (l == 0) ? __half2float(rc[1024]) : 0.f;
    clT = (l == 0) ? __half2float(rt[1024]) : 0.f;
  }
  const bool xtra = (lw == 0);
  float xrC[16], xrT[16], xlC = 0.f, xlT = 0.f;
  if (xtra) {
    const __half* rc = Cb + (long)1024 * 1025;
    const __half* rt = CTb + (long)1024 * 1025;
#pragma unroll
    for (int i = 0; i < 16; i++) {
      xrC[i] = __half2float(rc[l + 64 * i]);
      xrT[i] = __half2float(rt[l + 64 * i]);
    }
    if (l == 0) {
      xlC = __half2float(rc[1024]);
      xlT = __half2float(rt[1024]);
    }
  }

  unsigned tag = 0;
  for (int it = 0; it < iters; it++) {
    SK_ROUND(cr, clC, xrC, xlC, vb, ub);
    SK_ROUND(cc, clT, xrT, xlT, ub, vb);
  }
}

__global__ __launch_bounds__(256)
void ot_final(float* __restrict__ C, const u64t* __restrict__ u,
              const u64t* __restrict__ v, float norm) {
  long i = (long)blockIdx.x * 256 + threadIdx.x;
  if (i >= 4L * 1025 * 1025) return;
  const int b = (int)(i / 1050625);
  const long r = i - (long)b * 1050625;
  const int n = (int)(r / 1025);
  const int m = (int)(r - (long)n * 1025);
  const float uu = __uint_as_float((unsigned)u[b * 1025 + n]);
  const float vv = __uint_as_float((unsigned)v[b * 1025 + m]);
  C[i] += uu + vv - norm;
}

// ---------------- host ----------------
extern "C" void kernel_launch(void* const* d_in, const int* in_sizes, int n_in,
                              void* d_out, int out_size, void* d_ws, size_t ws_size,
                              hipStream_t stream) {
  (void)in_sizes; (void)n_in; (void)out_size; (void)ws_size;
  const float* descs0 = (const float*)d_in[0];
  const float* descs1 = (const float*)d_in[1];
  const float* Wq = (const float*)d_in[2];
  const float* bq = (const float*)d_in[3];
  const float* Wk = (const float*)d_in[4];
  const float* bk = (const float*)d_in[5];
  const float* Wv = (const float*)d_in[6];
  const float* bvv = (const float*)d_in[7];
  const float* Wm = (const float*)d_in[8];
  const float* bm = (const float*)d_in[9];
  const float* W1 = (const float*)d_in[10];
  const float* b1 = (const float*)d_in[11];
  const float* W2 = (const float*)d_in[12];
  const float* b2 = (const float*)d_in[13];
  const float* Wf = (const float*)d_in[14];
  const float* bff = (const float*)d_in[15];
  const float* alpha = (const float*)d_in[16];

  char* ws = (char*)d_ws;
  size_t off = 0;
  auto alloc = [&](size_t bytes) -> void* {
    off = (off + 255) & ~(size_t)255;
    void* p = ws + off;
    off += bytes;
    return p;
  };

  bf16* wL = (bf16*)alloc(2359296L * 2);           // rotating per-layer weights (4.5 MB)
  float* bqkv = (float*)alloc(1536 * 4);
  bf16* WfB = (bf16*)alloc(512L * 512 * 2);
  bf16* wcAll = (bf16*)alloc(12L * 1024 * 512 * 2);  // folded W1R@Wm' (12 MB)
  float* bcAll = (float*)alloc(12L * 1024 * 4);      // folded bias
  float* Xf = (float*)alloc(8L * 1024 * 512 * 4);  // fp32 residual stream
  bf16* Yb = (bf16*)alloc(8L * 1024 * 1024 * 2);   // [img][n][1024]: 0:512 x, 512:1024 attnO
  bf16* QKVb = (bf16*)alloc(8L * 1024 * 1536 * 2); // [token][1536] q|k|v
  bf16* vchan = (bf16*)alloc(8L * 1024 * 512 * 2); // [img][512ch][1024tok]
  char* SCR = (char*)alloc(50331648);              // 48 MB: prep tmp / T1+Zb / Ch+CTh+mproj
  float* stats = (float*)alloc(12L * 16384 * 4);   // per-layer IN stats
  unsigned int* ctrArr = (unsigned int*)alloc(12L * 32 * 4);
  u64t* u = (u64t*)alloc(4L * 1025 * 8);           // (tag<<32 | f32) pairs
  u64t* v = (u64t*)alloc(4L * 1025 * 8);

  bf16* wqkv = wL;                  // [1536][512]
  bf16* w1m = wL + 786432;          // [1024][1024] merged [W1left | Wc]
  bf16* w2 = wL + 1835008;          // [512][1024]
  float* T1 = (float*)SCR;                 // 32 MB
  bf16* Zb = (bf16*)(SCR + 33554432);      // 16 MB
  bf16* w1rTmp = (bf16*)SCR;               // prep: 12 MB (pre-layer-loop only)
  bf16* wmTTmp = (bf16*)(SCR + 12582912);  // prep: 6 MB
  __half* Ch = (__half*)SCR;               // 8.4 MB fp16 couplings (post-layers)
  __half* CTh = (__half*)(SCR + 8405248);  // 8.4 MB fp16 transposed
  bf16* mproj = (bf16*)(SCR + 33554432);   // 8 MB (post-layers)
  float* coup = (float*)d_out;

  cvt_f2b<<<512, 256, 0, stream>>>(Wf, WfB, 512L * 512);
  init_x<<<4096, 256, 0, stream>>>(descs0, descs1, Xf, Yb);
  // zero stats + ctr span in one memset
  hipMemsetAsync(stats, 0, ((char*)(ctrArr + 12 * 32) - (char*)stats), stream);

  auto gemm = [&](int ntile, const bf16* A, const bf16* B, int M, int N, int K,
                  int lda, int ldb, long sAimg, long sAh, long sBimg, long sBh,
                  int Z, int ZH, int cross, float scale, const float* bias,
                  float* Cf, int ldcf, long sCfImg, long sCfH,
                  bf16* Cb, int ldcb, long sCbImg, long sCbH,
                  __half* Ch_, int ldch, long sChImg, long sChH,
                  const float* resid) {
    GemmP p;
    p.A = A; p.B = B; p.M = M; p.N = N; p.K = K; p.lda = lda; p.ldb = ldb;
    p.sAimg = sAimg; p.sAh = sAh; p.sBimg = sBimg; p.sBh = sBh;
    p.ZH = ZH; p.cross = cross; p.scale = scale; p.bias = bias;
    p.Cf = Cf; p.ldcf = ldcf; p.sCfImg = sCfImg; p.sCfH = sCfH;
    p.Cb = Cb; p.ldcb = ldcb; p.sCbImg = sCbImg; p.sCbH = sCbH;
    p.Ch = Ch_; p.ldch = ldch; p.sChImg = sChImg; p.sChH = sChH;
    p.resid = resid;
    dim3 g((unsigned)((N + ntile - 1) / ntile), (unsigned)((M + 127) / 128), (unsigned)Z);
    if (ntile == 128) gemm_bt<128><<<g, 256, 0, stream>>>(p);
    else gemm_bt<64><<<g, 256, 0, stream>>>(p);
  };

  // ---- upfront fold: Wc[l] = W1R[l] @ wm'[l]  (batched Z=12), bc = b1 + W1R@bm ----
  cvt_prep<<<36864, 256, 0, stream>>>(W1, Wm, w1rTmp, wmTTmp);
  bc_calc<<<3072, 256, 0, stream>>>(W1, bm, b1, bcAll);
  gemm(128, w1rTmp, wmTTmp, 1024, 512, 512, 512, 512, 524288, 0, 262144, 0,
       12, 1, 0, 1.f, nullptr,
       nullptr, 0, 0, 0, wcAll, 512, 524288, 0, nullptr, 0, 0, 0, nullptr);

  for (int i = 0; i < 12; i++) {
    const int cross = i & 1;  // NAMES = self,cross,self,...
    cvt_layer<<<9222, 256, 0, stream>>>(Wq, Wk, Wv, W1, W2, wcAll, bq, bk, bvv, i, wL, bqkv);

    // fused QKV: [8192,1536] = Yb[:, :512] x Wqkv^T
    gemm(128, Yb, wqkv, 8192, 1536, 512, 1024, 512, 0, 0, 0, 0, 1, 1, 0, 1.f, bqkv,
         nullptr, 0, 0, 0, QKVb, 1536, 0, 0, nullptr, 0, 0, 0, nullptr);
    // v channels -> channel-major
    transpose_2b<<<dim3(8, 16, 8), 256, 0, stream>>>((const unsigned short*)(QKVb + 1024),
                                                     1536, (unsigned short*)vchan);
    // fused flash attention -> Yb[:, 512:1024] (O in head-major channel order)
    attn_fused<<<dim3(8, 1, 64), 256, 0, stream>>>(QKVb, vchan, Yb, cross);

    // T1 = [W1L | Wc] x [x; O] + bc  (msg GEMM folded away)
    gemm(128, Yb, w1m, 8192, 1024, 1024, 1024, 1024, 0, 0, 0, 0, 1, 1, 0, 1.f,
         bcAll + i * 1024,
         T1, 1024, 0, 0, nullptr, 0, 0, 0, nullptr, 0, 0, 0, nullptr);
    // fused instance-norm (stats + grid-sync + apply)
    in_norm<<<1024, 256, 0, stream>>>(T1, Zb, stats + (long)i * 16384, ctrArr + i * 32);
    // x += W2 z + b2 : fp32 residual into Xf, bf16 mirror into Yb[:, :512]
    gemm(128, Zb, w2, 8192, 512, 1024, 1024, 1024, 0, 0, 0, 0, 1, 1, 0, 1.f, b2 + i * 512,
         Xf, 512, 0, 0, Yb, 1024, 0, 0, nullptr, 0, 0, 0, Xf);
  }

  // final projection + score matrix into d_out
  gemm(128, Yb, WfB, 8192, 512, 512, 1024, 512, 0, 0, 0, 0, 1, 1, 0, 1.f, bff,
       nullptr, 0, 0, 0, mproj, 512, 0, 0, nullptr, 0, 0, 0, nullptr);
  gemm(128, mproj, mproj + 524288, 1024, 1024, 512, 512, 512,
       1048576, 0, 1048576, 0, 4, 1, 0,
       0.044194173824159216f, nullptr,
       coup, 1025, 1050625, 0, nullptr, 0, 0, 0, nullptr, 0, 0, 0, nullptr);
  coup_to_fp16<<<dim3(33, 33, 4), 256, 0, stream>>>(coup, alpha, Ch, CTh);

  hipMemsetAsync(u, 0, 4L * 1025 * 8, stream);
  hipMemsetAsync(v, 0, 4L * 1025 * 8, stream);
  const float NORM = -logf(2048.f);
  const float LOGN = logf(1024.f);
  int iters = 100;
  void* args[] = {(void*)&Ch, (void*)&CTh, (void*)&u, (void*)&v,
                  (void*)&NORM, (void*)&LOGN, (void*)&iters};
  hipLaunchCooperativeKernel((void*)sinkhorn_pers, dim3(SK_BLOCKS), dim3(1024), args, 0, stream);
  ot_final<<<16417, 256, 0, stream>>>(coup, u, v, NORM);
}

// Round 6
// 3370.705 us; speedup vs baseline: 1.3018x; 1.3018x over previous
//
#include <hip/hip_runtime.h>
#include <hip/hip_bf16.h>
#include <hip/hip_fp16.h>
#include <cmath>

using bf16 = __hip_bfloat16;
typedef __attribute__((ext_vector_type(8))) short short8;
typedef __attribute__((ext_vector_type(4))) float floatx4;
typedef unsigned long long u64t;

__device__ __forceinline__ void lds_load16(void* lds, const void* g) {
  __builtin_amdgcn_global_load_lds(
      (const __attribute__((address_space(1))) void*)g,
      (__attribute__((address_space(3))) void*)lds, 16, 0, 0);
}

// ---------------- generic BT GEMM: C[M][N] = scale*(A[M][K] x B[N][K]^T) + bias ----------
struct GemmP {
  const bf16* A; const bf16* B;
  int M, N, K, lda, ldb;
  long sAimg, sAh, sBimg, sBh;
  int ZH, cross;
  float scale;
  const float* bias;
  float* Cf; int ldcf; long sCfImg, sCfH;
  bf16* Cb; int ldcb; long sCbImg, sCbH;
  __half* Ch; int ldch; long sChImg, sChH;
  const float* resid;  // fp32, same indexing as Cf
};

template <int NTILE>  // 128: 4 waves x (64x64); 64: 4 waves x (32x64)
__global__ __launch_bounds__(256, 2)
void gemm_bt(GemmP p) {
  __shared__ __align__(16) bf16 As[128 * 32];
  __shared__ __align__(16) bf16 Bs[NTILE * 32];
  constexpr int MI = (NTILE == 128) ? 4 : 2;
  const int z = blockIdx.z;
  const int imgA = z / p.ZH;
  const int h = z - imgA * p.ZH;
  const int imgB = imgA ^ p.cross;
  const bf16* Ab = p.A + (long)imgA * p.sAimg + (long)h * p.sAh;
  const bf16* Bb = p.B + (long)imgB * p.sBimg + (long)h * p.sBh;
  const int m0 = blockIdx.y * 128, n0 = blockIdx.x * NTILE;
  const int t = threadIdx.x, w = t >> 6, l = t & 63;
  const int lr = l >> 2, lk = (l & 3) * 8;   // staging: row-in-chunk, k-elem offset
  const int fr = l & 15, fk = (l >> 4) * 8;  // fragment: row-in-16tile, k offset

  const bf16* aG0 = Ab + (long)(m0 + w * 16 + lr) * p.lda + lk;
  const bf16* aG1 = aG0 + (long)64 * p.lda;
  const bf16* bG0 = Bb + (long)(n0 + w * 16 + lr) * p.ldb + lk;
  const bf16* bG1 = bG0 + (long)64 * p.ldb;
  bf16* aL0 = &As[w * 16 * 32];
  bf16* aL1 = &As[(w + 4) * 16 * 32];
  bf16* bL0 = &Bs[w * 16 * 32];
  bf16* bL1 = &Bs[(w + 4) * 16 * 32];
  const int wr = (NTILE == 128) ? (w >> 1) * 64 : w * 32;
  const int wc = (NTILE == 128) ? (w & 1) * 64 : 0;

  floatx4 zero4 = {0.f, 0.f, 0.f, 0.f};
  floatx4 acc[MI][4];
#pragma unroll
  for (int i = 0; i < MI; i++)
#pragma unroll
    for (int j = 0; j < 4; j++) acc[i][j] = zero4;

  for (int k0 = 0; k0 < p.K; k0 += 32) {
    lds_load16(aL0, aG0 + k0);
    lds_load16(aL1, aG1 + k0);
    lds_load16(bL0, bG0 + k0);
    if (NTILE == 128) lds_load16(bL1, bG1 + k0);
    __syncthreads();
    short8 af[MI], bfv[4];
#pragma unroll
    for (int i = 0; i < MI; i++)
      af[i] = *(const short8*)&As[(wr + i * 16 + fr) * 32 + fk];
#pragma unroll
    for (int j = 0; j < 4; j++)
      bfv[j] = *(const short8*)&Bs[(wc + j * 16 + fr) * 32 + fk];
#pragma unroll
    for (int i = 0; i < MI; i++)
#pragma unroll
      for (int j = 0; j < 4; j++)
        acc[i][j] = __builtin_amdgcn_mfma_f32_16x16x32_bf16(af[i], bfv[j], acc[i][j], 0, 0, 0);
    __syncthreads();
  }

  // epilogue: D[row][col], col = lane&15, row = (lane>>4)*4 + r  [m89-verified layout]
  const int cl = l & 15, rq = (l >> 4) * 4;
  const long cfBase = (long)imgA * p.sCfImg + (long)h * p.sCfH;
  const long cbBase = (long)imgA * p.sCbImg + (long)h * p.sCbH;
  const long chBase = (long)imgA * p.sChImg + (long)h * p.sChH;
#pragma unroll
  for (int j = 0; j < 4; j++) {
    const int col = n0 + wc + j * 16 + cl;
    if (col >= p.N) continue;
    const float bv = p.bias ? p.bias[col] : 0.f;
#pragma unroll
    for (int i = 0; i < MI; i++) {
#pragma unroll
      for (int r = 0; r < 4; r++) {
        const int row = m0 + wr + i * 16 + rq + r;
        float val = acc[i][j][r] * p.scale + bv;
        if (p.resid) val += p.resid[cfBase + (long)row * p.ldcf + col];
        if (p.Cf) p.Cf[cfBase + (long)row * p.ldcf + col] = val;
        if (p.Cb) p.Cb[cbBase + (long)row * p.ldcb + col] = __float2bfloat16(val);
        if (p.Ch) p.Ch[chBase + (long)row * p.ldch + col] = __float2half(val);
      }
    }
  }
}

// ---------------- fused flash attention (r3-verified) ----------------
// Writes directly into Yb[:, 512:1024] (the old msg slot): O in head-major channels,
// which matches the wm'-column space that the folded Wc was built in.
__global__ __launch_bounds__(256, 2)
void attn_fused(const bf16* __restrict__ QKV, const bf16* __restrict__ vchan,
                bf16* __restrict__ Yb, int cross) {
  __shared__ __align__(16) bf16 Qs[128 * 64];
  __shared__ __align__(16) bf16 Ks[64 * 64];
  __shared__ __align__(16) bf16 Vs[64 * 64];
  __shared__ __align__(16) bf16 Ps[128 * 64];
  const int z = blockIdx.z;
  const int img = z >> 3, h = z & 7;
  const int imgB = img ^ cross;
  const int q0 = blockIdx.x * 128;
  const int t = threadIdx.x, w = t >> 6, l = t & 63;
  const int g = l >> 4, fr = l & 15;
  const int wr = w * 32;

  {
    const bf16* src = QKV + ((long)(img * 1024 + q0)) * 1536 + h * 64;
#pragma unroll
    for (int k = 0; k < 4; k++) {
      const int chunk = t + k * 256;
      const int row = chunk >> 3, c16 = chunk & 7;
      const short8 vd = *(const short8*)(src + (long)row * 1536 + c16 * 8);
      *(short8*)((char*)Qs + row * 128 + ((c16 * 16) ^ ((row & 7) << 4))) = vd;
    }
  }
  __syncthreads();

  short8 qf[2][2];
#pragma unroll
  for (int i = 0; i < 2; i++)
#pragma unroll
    for (int ks = 0; ks < 2; ks++) {
      const int row = wr + i * 16 + fr;
      qf[i][ks] = *(const short8*)((const char*)Qs + row * 128 +
                                   ((ks * 64 + g * 16) ^ ((row & 7) << 4)));
    }

  floatx4 zero4 = {0.f, 0.f, 0.f, 0.f};
  floatx4 Oa[2][4];
  float m_run[2][4], l_run[2][4];
#pragma unroll
  for (int i = 0; i < 2; i++)
#pragma unroll
    for (int r = 0; r < 4; r++) { m_run[i][r] = -3.0e38f; l_run[i][r] = 0.f; }
#pragma unroll
  for (int i = 0; i < 2; i++)
#pragma unroll
    for (int jd = 0; jd < 4; jd++) Oa[i][jd] = zero4;

  const bf16* ksrc0 = QKV + ((long)(imgB * 1024)) * 1536 + 512 + h * 64;
  const bf16* vsrc0 = vchan + (long)imgB * 524288 + (long)(h * 64) * 1024;

  for (int kv = 0; kv < 16; kv++) {
    const int kv0 = kv * 64;
#pragma unroll
    for (int k = 0; k < 2; k++) {
      const int ch = t + k * 256;
      const int row = ch >> 3, c16 = ch & 7;
      const short8 vd = *(const short8*)(ksrc0 + (long)(kv0 + row) * 1536 + c16 * 8);
      *(short8*)((char*)Ks + row * 128 + ((c16 * 16) ^ ((row & 7) << 4))) = vd;
    }
#pragma unroll
    for (int k = 0; k < 2; k++) {
      const int ch = t + k * 256;
      const int row = ch >> 3, c16 = ch & 7;
      const short8 vd = *(const short8*)(vsrc0 + (long)row * 1024 + kv0 + c16 * 8);
      *(short8*)((char*)Vs + row * 128 + ((c16 * 16) ^ ((row & 7) << 4))) = vd;
    }
    __syncthreads();

    floatx4 sa[2][4];
#pragma unroll
    for (int i = 0; i < 2; i++)
#pragma unroll
      for (int j = 0; j < 4; j++) sa[i][j] = zero4;
    short8 bk[4][2];
#pragma unroll
    for (int j = 0; j < 4; j++)
#pragma unroll
      for (int ks = 0; ks < 2; ks++) {
        const int row = j * 16 + fr;
        bk[j][ks] = *(const short8*)((const char*)Ks + row * 128 +
                                     ((ks * 64 + g * 16) ^ ((row & 7) << 4)));
      }
#pragma unroll
    for (int i = 0; i < 2; i++)
#pragma unroll
      for (int j = 0; j < 4; j++)
#pragma unroll
        for (int ks = 0; ks < 2; ks++)
          sa[i][j] = __builtin_amdgcn_mfma_f32_16x16x32_bf16(qf[i][ks], bk[j][ks], sa[i][j], 0, 0, 0);

#pragma unroll
    for (int i = 0; i < 2; i++) {
#pragma unroll
      for (int r = 0; r < 4; r++) {
        float mx = -3.0e38f;
#pragma unroll
        for (int j = 0; j < 4; j++) {
          sa[i][j][r] *= 0.125f;
          mx = fmaxf(mx, sa[i][j][r]);
        }
#pragma unroll
        for (int o = 1; o < 16; o <<= 1) mx = fmaxf(mx, __shfl_xor(mx, o));
        const float mnew = fmaxf(m_run[i][r], mx);
        const float corr = __expf(m_run[i][r] - mnew);
        m_run[i][r] = mnew;
        float ps = 0.f;
#pragma unroll
        for (int j = 0; j < 4; j++) {
          const float pv = __expf(sa[i][j][r] - mnew);
          sa[i][j][r] = pv;
          ps += pv;
        }
#pragma unroll
        for (int o = 1; o < 16; o <<= 1) ps += __shfl_xor(ps, o);
        l_run[i][r] = l_run[i][r] * corr + ps;
#pragma unroll
        for (int jd = 0; jd < 4; jd++) Oa[i][jd][r] *= corr;
      }
    }

#pragma unroll
    for (int i = 0; i < 2; i++)
#pragma unroll
      for (int j = 0; j < 4; j++)
#pragma unroll
        for (int r = 0; r < 4; r++) {
          const int row = wr + i * 16 + g * 4 + r;
          const int colB = j * 32 + fr * 2;
          *(bf16*)((char*)Ps + row * 128 + (colB ^ ((row & 7) << 4))) =
              __float2bfloat16(sa[i][j][r]);
        }

    short8 pf[2][2], vf[4][2];
#pragma unroll
    for (int i = 0; i < 2; i++)
#pragma unroll
      for (int ks = 0; ks < 2; ks++) {
        const int row = wr + i * 16 + fr;
        pf[i][ks] = *(const short8*)((const char*)Ps + row * 128 +
                                     ((ks * 64 + g * 16) ^ ((row & 7) << 4)));
      }
#pragma unroll
    for (int jd = 0; jd < 4; jd++)
#pragma unroll
      for (int ks = 0; ks < 2; ks++) {
        const int row = jd * 16 + fr;
        vf[jd][ks] = *(const short8*)((const char*)Vs + row * 128 +
                                      ((ks * 64 + g * 16) ^ ((row & 7) << 4)));
      }
#pragma unroll
    for (int i = 0; i < 2; i++)
#pragma unroll
      for (int jd = 0; jd < 4; jd++)
#pragma unroll
        for (int ks = 0; ks < 2; ks++)
          Oa[i][jd] = __builtin_amdgcn_mfma_f32_16x16x32_bf16(pf[i][ks], vf[jd][ks], Oa[i][jd], 0, 0, 0);
    __syncthreads();
  }

  // epilogue: O /= l, write Yb[img][token][512 + h*64 + d]
#pragma unroll
  for (int i = 0; i < 2; i++) {
#pragma unroll
    for (int r = 0; r < 4; r++) {
      const float inv = 1.f / l_run[i][r];
      const int qrow = q0 + wr + i * 16 + g * 4 + r;
      bf16* dst = Yb + ((long)img * 1024 + qrow) * 1024 + 512 + h * 64;
#pragma unroll
      for (int jd = 0; jd < 4; jd++)
        dst[jd * 16 + fr] = __float2bfloat16(Oa[i][jd][r] * inv);
    }
  }
}

// ---------------- elementwise / helper kernels ----------------
__global__ __launch_bounds__(256)
void cvt_f2b(const float* __restrict__ in, bf16* __restrict__ out, long n) {
  long i = (long)blockIdx.x * 256 + threadIdx.x;
  const long stride = (long)gridDim.x * 256;
  for (; i < n; i += stride) out[i] = __float2bfloat16(in[i]);
}

// upfront: bf16 conversions for the Wm->W1 fold.
__global__ __launch_bounds__(256)
void cvt_prep(const float* __restrict__ W1, const float* __restrict__ Wm,
              bf16* __restrict__ w1r, bf16* __restrict__ wmT) {
  const long i = (long)blockIdx.x * 256 + threadIdx.x;
  if (i < 6291456L) {
    const int lay = (int)(i >> 19);
    const long r = i & 524287;
    const int o = (int)(r >> 9), k = (int)(r & 511);
    w1r[i] = __float2bfloat16(W1[(long)lay * 1048576 + (long)o * 1024 + 512 + k]);
  } else if (i < 9437184L) {
    const long j = i - 6291456L;
    const int lay = (int)(j >> 18);
    const long r = j & 262143;
    const int c = (int)(r >> 9), ii = (int)(r & 511);
    wmT[j] = __float2bfloat16(Wm[(long)lay * 262144 + (long)ii * 512 + (c & 63) * 8 + (c >> 6)]);
  }
}

// upfront: bc[l][o] = b1[l][o] + sum_i W1[l][o][512+i]*bm[l][i]  (wave per output)
__global__ __launch_bounds__(256)
void bc_calc(const float* __restrict__ W1, const float* __restrict__ bm,
             const float* __restrict__ b1, float* __restrict__ bc) {
  const int w = threadIdx.x >> 6, l = threadIdx.x & 63;
  const int og = blockIdx.x * 4 + w;  // 0..12287
  const int lay = og >> 10, o = og & 1023;
  const float* wrow = W1 + (long)lay * 1048576 + (long)o * 1024 + 512;
  const float* bmr = bm + lay * 512;
  float s = 0.f;
#pragma unroll
  for (int j = 0; j < 8; j++) s += wrow[l + 64 * j] * bmr[l + 64 * j];
#pragma unroll
  for (int o2 = 32; o2 >= 1; o2 >>= 1) s += __shfl_xor(s, o2);
  if (l == 0) bc[og] = b1[og] + s;
}

// per-layer weight conversion (4.5 MB rotating):
// [0:768K) wqkv | [768K:1.75M) w1merged = [W1left | Wc] | [1.75M:2.25M) w2
__global__ __launch_bounds__(256)
void cvt_layer(const float* __restrict__ Wq, const float* __restrict__ Wk,
               const float* __restrict__ Wv, const float* __restrict__ W1,
               const float* __restrict__ W2, const bf16* __restrict__ wcAll,
               const float* __restrict__ bq, const float* __restrict__ bk,
               const float* __restrict__ bv,
               int layer, bf16* __restrict__ out, float* __restrict__ bqkv) {
  const long i = (long)blockIdx.x * 256 + threadIdx.x;
  if (i >= 2359296L + 1536) return;
  if (i >= 2359296L) {
    const int j = (int)(i - 2359296L);
    float b;
    if (j < 512) b = bq[layer * 512 + j];
    else if (j < 1024) b = bk[layer * 512 + j - 512];
    else b = bv[layer * 512 + j - 1024];
    bqkv[j] = b;
    return;
  }
  if (i < 786432) {
    float v;
    if (i < 262144) v = Wq[(long)layer * 262144 + i];
    else if (i < 524288) v = Wk[(long)layer * 262144 + i - 262144];
    else v = Wv[(long)layer * 262144 + i - 524288];
    out[i] = __float2bfloat16(v);
  } else if (i < 1835008) {
    const long j = i - 786432;
    const int o = (int)(j >> 10), k = (int)(j & 1023);
    if (k < 512)
      out[i] = __float2bfloat16(W1[(long)layer * 1048576 + (long)o * 1024 + k]);
    else
      out[i] = wcAll[(long)layer * 524288 + (long)o * 512 + (k - 512)];
  } else {
    const long j = i - 1835008;
    out[i] = __float2bfloat16(W2[(long)layer * 524288 + j]);
  }
}

__global__ __launch_bounds__(256)
void init_x(const float* __restrict__ d0, const float* __restrict__ d1,
            float* __restrict__ Xf, bf16* __restrict__ Yb) {
  long i = (long)blockIdx.x * 256 + threadIdx.x;
  const long stride = (long)gridDim.x * 256;
  const long n = 8L * 1024 * 512;
  for (; i < n; i += stride) {
    const int d = (int)(i & 511);
    const long nn = i >> 9;  // img*1024 + row
    const int img = (int)(nn >> 10);
    const int row = (int)(nn & 1023);
    const int b = img >> 1, s = img & 1;
    const float v = (s ? d1 : d0)[((long)b * 1024 + row) * 512 + d];
    Xf[i] = v;
    Yb[(nn << 10) + d] = __float2bfloat16(v);
  }
}

// transpose [8][1024][512-cols-of-ldi] (2-byte elems) -> [8][512][1024]
__global__ __launch_bounds__(256)
void transpose_2b(const unsigned short* __restrict__ in, int ldi,
                  unsigned short* __restrict__ out) {
  __shared__ unsigned short tile[64][65];
  const int img = blockIdx.z;
  const int m0 = blockIdx.y * 64, c0 = blockIdx.x * 64;
  const int col = threadIdx.x & 63, r0 = threadIdx.x >> 6;
  const unsigned short* ip = in + ((long)img * 1024 + m0) * ldi + c0;
#pragma unroll
  for (int i = 0; i < 16; i++) { int r = r0 + i * 4; tile[r][col] = ip[(long)r * ldi + col]; }
  __syncthreads();
  unsigned short* op = out + ((long)img * 512 + c0) * 1024 + m0;
#pragma unroll
  for (int i = 0; i < 16; i++) { int r = r0 + i * 4; op[(long)r * 1024 + col] = tile[col][r]; }
}

// instance-norm stats (r3-proven): column sums over n per (img, channel);
// per-layer stats slice pre-zeroed by one upfront memset. Only 8 atomics/cell.
__global__ __launch_bounds__(256)
void in_stats(const float* __restrict__ T1, float* __restrict__ stats) {
  const int img = blockIdx.z;
  const int c = blockIdx.x * 256 + threadIdx.x;
  const int nb = blockIdx.y;
  const float* p = T1 + ((long)img * 1024 + nb * 128) * 1024 + c;
  float s = 0.f, s2 = 0.f;
#pragma unroll 4
  for (int i = 0; i < 128; i++) { const float x = p[(long)i * 1024]; s += x; s2 += x * x; }
  atomicAdd(&stats[img * 2048 + c], s);
  atomicAdd(&stats[img * 2048 + 1024 + c], s2);
}

__global__ __launch_bounds__(256)
void in_apply(const float* __restrict__ T1, const float* __restrict__ stats,
              bf16* __restrict__ Z) {
  long i = (long)blockIdx.x * 256 + threadIdx.x;
  const long stride = (long)gridDim.x * 256;
  for (; i < 8L * 1024 * 1024; i += stride) {
    const int c = (int)(i & 1023);
    const int img = (int)(i >> 20);
    const float mean = stats[img * 2048 + c] * (1.f / 1024.f);
    const float var = fmaxf(stats[img * 2048 + 1024 + c] * (1.f / 1024.f) - mean * mean, 0.f);
    const float zz = (T1[i] - mean) * rsqrtf(var + 1e-5f);
    Z[i] = __float2bfloat16(fmaxf(zz, 0.f));
  }
}

// fp32 coupling -> fp16 copy + fp16 transpose, with bin rows/cols filled inline
__global__ __launch_bounds__(256)
void coup_to_fp16(float* __restrict__ io, const float* __restrict__ alpha,
                  __half* __restrict__ outN, __half* __restrict__ outT) {
  __shared__ float tile[32][33];
  const float a = *alpha;
  const int b = blockIdx.z;
  const int x0 = blockIdx.x * 32, y0 = blockIdx.y * 32;
  const int lx = threadIdx.x & 31, ly = threadIdx.x >> 5;  // ly 0..7
#pragma unroll
  for (int i = 0; i < 4; i++) {
    const int y = ly + i * 8;
    if (y0 + y < 1025 && x0 + lx < 1025) {
      const long idx = ((long)b * 1025 + y0 + y) * 1025 + x0 + lx;
      const bool edge = (y0 + y == 1024) || (x0 + lx == 1024);
      float vv;
      if (edge) { vv = a; io[idx] = a; }
      else vv = io[idx];
      tile[y][lx] = vv;
      outN[idx] = __float2half(vv);
    }
  }
  __syncthreads();
#pragma unroll
  for (int i = 0; i < 4; i++) {
    const int y = ly + i * 8;
    if (x0 + y < 1025 && y0 + lx < 1025)
      outT[((long)b * 1025 + x0 + y) * 1025 + y0 + lx] = __float2half(tile[lx][y]);
  }
}

// -------- persistent Sinkhorn (r9 structure: per-lane spin on tagged u64 entries) ----
#define SK_BLOCKS 256

#define SK_ROUND(CREG, CLAST, XREG, XLAST, SRC, DST)                            \
  {                                                                             \
    u64t pr;                                                                    \
    while ((unsigned)((pr = __hip_atomic_load(&(SRC)[t], __ATOMIC_RELAXED,      \
                                              __HIP_MEMORY_SCOPE_AGENT)) >>    \
                      32) != tag)                                               \
      __builtin_amdgcn_s_sleep(1);                                              \
    sv[t] = __uint_as_float((unsigned)pr);                                      \
    if (t == 0) {                                                               \
      u64t qr;                                                                  \
      while ((unsigned)((qr = __hip_atomic_load(&(SRC)[1024], __ATOMIC_RELAXED, \
                                                __HIP_MEMORY_SCOPE_AGENT)) >>  \
                        32) != tag)                                             \
        __builtin_amdgcn_s_sleep(1);                                            \
      sv[1024] = __uint_as_float((unsigned)qr);                                 \
    }                                                                           \
    __syncthreads();                                                            \
    float M = (l == 0) ? ((CLAST) + sv[1024]) : -3.0e38f;                       \
    const float extra = M;                                                      \
    float x[16];                                                                \
    _Pragma("unroll") for (int i = 0; i < 16; i++) {                            \
      x[i] = (CREG)[i] + sv[l + 64 * i];                                        \
      M = fmaxf(M, x[i]);                                                       \
    }                                                                           \
    _Pragma("unroll") for (int o = 32; o >= 1; o >>= 1)                         \
        M = fmaxf(M, __shfl_xor(M, o));                                         \
    float S = (l == 0) ? __expf(extra - M) : 0.f;                               \
    _Pragma("unroll") for (int i = 0; i < 16; i++) S += __expf(x[i] - M);       \
    _Pragma("unroll") for (int o = 32; o >= 1; o >>= 1) S += __shfl_xor(S, o);  \
    if (l == 0) {                                                               \
      const float val = norm - (M + __logf(S));                                 \
      const u64t pk = ((u64t)(tag + 1) << 32) | (u64t)__float_as_uint(val);     \
      __hip_atomic_store(&(DST)[lw], pk, __ATOMIC_RELAXED,                      \
                         __HIP_MEMORY_SCOPE_AGENT);                             \
    }                                                                           \
    if (xtra) {                                                                 \
      float M2 = (l == 0) ? ((XLAST) + sv[1024]) : -3.0e38f;                    \
      const float e2 = M2;                                                      \
      float y[16];                                                              \
      _Pragma("unroll") for (int i = 0; i < 16; i++) {                          \
        y[i] = (XREG)[i] + sv[l + 64 * i];                                      \
        M2 = fmaxf(M2, y[i]);                                                   \
      }                                                                         \
      _Pragma("unroll") for (int o = 32; o >= 1; o >>= 1)                       \
          M2 = fmaxf(M2, __shfl_xor(M2, o));                                    \
      float S2 = (l == 0) ? __expf(e2 - M2) : 0.f;                              \
      _Pragma("unroll") for (int i = 0; i < 16; i++) S2 += __expf(y[i] - M2);   \
      _Pragma("unroll") for (int o = 32; o >= 1; o >>= 1)                       \
          S2 += __shfl_xor(S2, o);                                              \
      if (l == 0) {                                                             \
        const float v2 = (logN + norm) - (M2 + __logf(S2));                     \
        const u64t pk2 = ((u64t)(tag + 1) << 32) | (u64t)__float_as_uint(v2);   \
        __hip_atomic_store(&(DST)[1024], pk2, __ATOMIC_RELAXED,                 \
                           __HIP_MEMORY_SCOPE_AGENT);                           \
      }                                                                         \
    }                                                                           \
    tag++;                                                                      \
    __syncthreads();                                                            \
  }

__global__ __launch_bounds__(1024)
void sinkhorn_pers(const __half* __restrict__ C, const __half* __restrict__ CT,
                   u64t* __restrict__ u, u64t* __restrict__ v,
                   float norm, float logN, int iters) {
  __shared__ float sv[1025];
  const int t = threadIdx.x;
  const int w = t >> 6, l = t & 63;
  const int b = blockIdx.x >> 6;   // batch 0..3
  const int kb = blockIdx.x & 63;  // block within batch
  const int lw = kb * 16 + w;      // wave's row within batch: 0..1023
  const __half* Cb = C + (long)b * 1050625;
  const __half* CTb = CT + (long)b * 1050625;
  u64t* ub = u + b * 1025;
  u64t* vb = v + b * 1025;

  float cr[16], cc[16];
  float clC, clT;
  {
    const __half* rc = Cb + (long)lw * 1025;
    const __half* rt = CTb + (long)lw * 1025;
#pragma unroll
    for (int i = 0; i < 16; i++) {
      cr[i] = __half2float(rc[l + 64 * i]);
      cc[i] = __half2float(rt[l + 64 * i]);
    }
    clC = (l == 0) ? __half2float(rc[1024]) : 0.f;
    clT = (l == 0) ? __half2float(rt[1024]) : 0.f;
  }
  const bool xtra = (lw == 0);
  float xrC[16], xrT[16], xlC = 0.f, xlT = 0.f;
  if (xtra) {
    const __half* rc = Cb + (long)1024 * 1025;
    const __half* rt = CTb + (long)1024 * 1025;
#pragma unroll
    for (int i = 0; i < 16; i++) {
      xrC[i] = __half2float(rc[l + 64 * i]);
      xrT[i] = __half2float(rt[l + 64 * i]);
    }
    if (l == 0) {
      xlC = __half2float(rc[1024]);
      xlT = __half2float(rt[1024]);
    }
  }

  unsigned tag = 0;
  for (int it = 0; it < iters; it++) {
    SK_ROUND(cr, clC, xrC, xlC, vb, ub);
    SK_ROUND(cc, clT, xrT, xlT, ub, vb);
  }
}

__global__ __launch_bounds__(256)
void ot_final(float* __restrict__ C, const u64t* __restrict__ u,
              const u64t* __restrict__ v, float norm) {
  long i = (long)blockIdx.x * 256 + threadIdx.x;
  if (i >= 4L * 1025 * 1025) return;
  const int b = (int)(i / 1050625);
  const long r = i - (long)b * 1050625;
  const int n = (int)(r / 1025);
  const int m = (int)(r - (long)n * 1025);
  const float uu = __uint_as_float((unsigned)u[b * 1025 + n]);
  const float vv = __uint_as_float((unsigned)v[b * 1025 + m]);
  C[i] += uu + vv - norm;
}

// ---------------- host ----------------
extern "C" void kernel_launch(void* const* d_in, const int* in_sizes, int n_in,
                              void* d_out, int out_size, void* d_ws, size_t ws_size,
                              hipStream_t stream) {
  (void)in_sizes; (void)n_in; (void)out_size; (void)ws_size;
  const float* descs0 = (const float*)d_in[0];
  const float* descs1 = (const float*)d_in[1];
  const float* Wq = (const float*)d_in[2];
  const float* bq = (const float*)d_in[3];
  const float* Wk = (const float*)d_in[4];
  const float* bk = (const float*)d_in[5];
  const float* Wv = (const float*)d_in[6];
  const float* bvv = (const float*)d_in[7];
  const float* Wm = (const float*)d_in[8];
  const float* bm = (const float*)d_in[9];
  const float* W1 = (const float*)d_in[10];
  const float* b1 = (const float*)d_in[11];
  const float* W2 = (const float*)d_in[12];
  const float* b2 = (const float*)d_in[13];
  const float* Wf = (const float*)d_in[14];
  const float* bff = (const float*)d_in[15];
  const float* alpha = (const float*)d_in[16];

  char* ws = (char*)d_ws;
  size_t off = 0;
  auto alloc = [&](size_t bytes) -> void* {
    off = (off + 255) & ~(size_t)255;
    void* p = ws + off;
    off += bytes;
    return p;
  };

  bf16* wL = (bf16*)alloc(2359296L * 2);           // rotating per-layer weights (4.5 MB)
  float* bqkv = (float*)alloc(1536 * 4);
  bf16* WfB = (bf16*)alloc(512L * 512 * 2);
  bf16* wcAll = (bf16*)alloc(12L * 1024 * 512 * 2);  // folded W1R@Wm' (12 MB)
  float* bcAll = (float*)alloc(12L * 1024 * 4);      // folded bias
  float* Xf = (float*)alloc(8L * 1024 * 512 * 4);  // fp32 residual stream
  bf16* Yb = (bf16*)alloc(8L * 1024 * 1024 * 2);   // [img][n][1024]: 0:512 x, 512:1024 attnO
  bf16* QKVb = (bf16*)alloc(8L * 1024 * 1536 * 2); // [token][1536] q|k|v
  bf16* vchan = (bf16*)alloc(8L * 1024 * 512 * 2); // [img][512ch][1024tok]
  char* SCR = (char*)alloc(50331648);              // 48 MB: prep tmp / T1+Zb / Ch+CTh+mproj
  float* stats = (float*)alloc(12L * 16384 * 4);   // per-layer IN stats
  u64t* u = (u64t*)alloc(4L * 1025 * 8);           // (tag<<32 | f32) pairs
  u64t* v = (u64t*)alloc(4L * 1025 * 8);

  bf16* wqkv = wL;                  // [1536][512]
  bf16* w1m = wL + 786432;          // [1024][1024] merged [W1left | Wc]
  bf16* w2 = wL + 1835008;          // [512][1024]
  float* T1 = (float*)SCR;                 // 32 MB
  bf16* Zb = (bf16*)(SCR + 33554432);      // 16 MB
  bf16* w1rTmp = (bf16*)SCR;               // prep: 12 MB (pre-layer-loop only)
  bf16* wmTTmp = (bf16*)(SCR + 12582912);  // prep: 6 MB
  __half* Ch = (__half*)SCR;               // 8.4 MB fp16 couplings (post-layers)
  __half* CTh = (__half*)(SCR + 8405248);  // 8.4 MB fp16 transposed
  bf16* mproj = (bf16*)(SCR + 33554432);   // 8 MB (post-layers)
  float* coup = (float*)d_out;

  cvt_f2b<<<512, 256, 0, stream>>>(Wf, WfB, 512L * 512);
  init_x<<<4096, 256, 0, stream>>>(descs0, descs1, Xf, Yb);
  // zero all 12 layers' stats slices once
  hipMemsetAsync(stats, 0, 12L * 16384 * 4, stream);

  auto gemm = [&](int ntile, const bf16* A, const bf16* B, int M, int N, int K,
                  int lda, int ldb, long sAimg, long sAh, long sBimg, long sBh,
                  int Z, int ZH, int cross, float scale, const float* bias,
                  float* Cf, int ldcf, long sCfImg, long sCfH,
                  bf16* Cb, int ldcb, long sCbImg, long sCbH,
                  __half* Ch_, int ldch, long sChImg, long sChH,
                  const float* resid) {
    GemmP p;
    p.A = A; p.B = B; p.M = M; p.N = N; p.K = K; p.lda = lda; p.ldb = ldb;
    p.sAimg = sAimg; p.sAh = sAh; p.sBimg = sBimg; p.sBh = sBh;
    p.ZH = ZH; p.cross = cross; p.scale = scale; p.bias = bias;
    p.Cf = Cf; p.ldcf = ldcf; p.sCfImg = sCfImg; p.sCfH = sCfH;
    p.Cb = Cb; p.ldcb = ldcb; p.sCbImg = sCbImg; p.sCbH = sCbH;
    p.Ch = Ch_; p.ldch = ldch; p.sChImg = sChImg; p.sChH = sChH;
    p.resid = resid;
    dim3 g((unsigned)((N + ntile - 1) / ntile), (unsigned)((M + 127) / 128), (unsigned)Z);
    if (ntile == 128) gemm_bt<128><<<g, 256, 0, stream>>>(p);
    else gemm_bt<64><<<g, 256, 0, stream>>>(p);
  };

  // ---- upfront fold: Wc[l] = W1R[l] @ wm'[l]  (batched Z=12), bc = b1 + W1R@bm ----
  cvt_prep<<<36864, 256, 0, stream>>>(W1, Wm, w1rTmp, wmTTmp);
  bc_calc<<<3072, 256, 0, stream>>>(W1, bm, b1, bcAll);
  gemm(128, w1rTmp, wmTTmp, 1024, 512, 512, 512, 512, 524288, 0, 262144, 0,
       12, 1, 0, 1.f, nullptr,
       nullptr, 0, 0, 0, wcAll, 512, 524288, 0, nullptr, 0, 0, 0, nullptr);

  for (int i = 0; i < 12; i++) {
    const int cross = i & 1;  // NAMES = self,cross,self,...
    cvt_layer<<<9222, 256, 0, stream>>>(Wq, Wk, Wv, W1, W2, wcAll, bq, bk, bvv, i, wL, bqkv);

    // fused QKV: [8192,1536] = Yb[:, :512] x Wqkv^T
    gemm(128, Yb, wqkv, 8192, 1536, 512, 1024, 512, 0, 0, 0, 0, 1, 1, 0, 1.f, bqkv,
         nullptr, 0, 0, 0, QKVb, 1536, 0, 0, nullptr, 0, 0, 0, nullptr);
    // v channels -> channel-major
    transpose_2b<<<dim3(8, 16, 8), 256, 0, stream>>>((const unsigned short*)(QKVb + 1024),
                                                     1536, (unsigned short*)vchan);
    // fused flash attention -> Yb[:, 512:1024] (O in head-major channel order)
    attn_fused<<<dim3(8, 1, 64), 256, 0, stream>>>(QKVb, vchan, Yb, cross);

    // T1 = [W1L | Wc] x [x; O] + bc  (msg GEMM folded away)
    gemm(128, Yb, w1m, 8192, 1024, 1024, 1024, 1024, 0, 0, 0, 0, 1, 1, 0, 1.f,
         bcAll + i * 1024,
         T1, 1024, 0, 0, nullptr, 0, 0, 0, nullptr, 0, 0, 0, nullptr);
    // instance-norm (r3-proven two-kernel path; per-layer stats slice)
    in_stats<<<dim3(4, 8, 8), 256, 0, stream>>>(T1, stats + (long)i * 16384);
    in_apply<<<8192, 256, 0, stream>>>(T1, stats + (long)i * 16384, Zb);
    // x += W2 z + b2 : fp32 residual into Xf, bf16 mirror into Yb[:, :512]
    gemm(128, Zb, w2, 8192, 512, 1024, 1024, 1024, 0, 0, 0, 0, 1, 1, 0, 1.f, b2 + i * 512,
         Xf, 512, 0, 0, Yb, 1024, 0, 0, nullptr, 0, 0, 0, Xf);
  }

  // final projection + score matrix into d_out
  gemm(128, Yb, WfB, 8192, 512, 512, 1024, 512, 0, 0, 0, 0, 1, 1, 0, 1.f, bff,
       nullptr, 0, 0, 0, mproj, 512, 0, 0, nullptr, 0, 0, 0, nullptr);
  gemm(128, mproj, mproj + 524288, 1024, 1024, 512, 512, 512,
       1048576, 0, 1048576, 0, 4, 1, 0,
       0.044194173824159216f, nullptr,
       coup, 1025, 1050625, 0, nullptr, 0, 0, 0, nullptr, 0, 0, 0, nullptr);
  coup_to_fp16<<<dim3(33, 33, 4), 256, 0, stream>>>(coup, alpha, Ch, CTh);

  hipMemsetAsync(u, 0, 4L * 1025 * 8, stream);
  hipMemsetAsync(v, 0, 4L * 1025 * 8, stream);
  const float NORM = -logf(2048.f);
  const float LOGN = logf(1024.f);
  int iters = 100;
  void* args[] = {(void*)&Ch, (void*)&CTh, (void*)&u, (void*)&v,
                  (void*)&NORM, (void*)&LOGN, (void*)&iters};
  hipLaunchCooperativeKernel((void*)sinkhorn_pers, dim3(SK_BLOCKS), dim3(1024), args, 0, stream);
  ot_final<<<16417, 256, 0, stream>>>(coup, u, v, NORM);
}

// Round 8
// 3182.071 us; speedup vs baseline: 1.3790x; 1.0593x over previous
//
#include <hip/hip_runtime.h>
#include <hip/hip_bf16.h>
#include <hip/hip_fp16.h>
#include <cmath>

using bf16 = __hip_bfloat16;
typedef __attribute__((ext_vector_type(8))) short short8;
typedef __attribute__((ext_vector_type(4))) short shortx4;
typedef __attribute__((ext_vector_type(4))) float floatx4;
typedef unsigned long long u64t;

__device__ __forceinline__ void lds_load16(void* lds, const void* g) {
  __builtin_amdgcn_global_load_lds(
      (const __attribute__((address_space(1))) void*)g,
      (__attribute__((address_space(3))) void*)lds, 16, 0, 0);
}

// ---------------- generic BT GEMM: C[M][N] = scale*(A[M][K] x B[N][K]^T) + bias ----------
// Extras: Cv/vColOfs = transposed bf16 side-output for cols>=vColOfs (replaces
// transpose_2b); statsOut = per-(img,col) sum/sumsq atomics (replaces in_stats).
struct GemmP {
  const bf16* A; const bf16* B;
  int M, N, K, lda, ldb;
  long sAimg, sAh, sBimg, sBh;
  int ZH, cross;
  float scale;
  const float* bias;
  float* Cf; int ldcf; long sCfImg, sCfH;
  bf16* Cb; int ldcb; long sCbImg, sCbH;
  __half* Ch; int ldch; long sChImg, sChH;
  const float* resid;  // fp32, same indexing as Cf
  bf16* Cv; int vColOfs;
  float* statsOut;
};

template <int NTILE>  // 128: 4 waves x (64x64); 64: 4 waves x (32x64)
__global__ __launch_bounds__(256, 2)
void gemm_bt(GemmP p) {
  __shared__ __align__(16) bf16 As[128 * 32];
  __shared__ __align__(16) bf16 Bs[NTILE * 32];
  constexpr int MI = (NTILE == 128) ? 4 : 2;
  const int z = blockIdx.z;
  const int imgA = z / p.ZH;
  const int h = z - imgA * p.ZH;
  const int imgB = imgA ^ p.cross;
  const bf16* Ab = p.A + (long)imgA * p.sAimg + (long)h * p.sAh;
  const bf16* Bb = p.B + (long)imgB * p.sBimg + (long)h * p.sBh;
  const int m0 = blockIdx.y * 128, n0 = blockIdx.x * NTILE;
  const int t = threadIdx.x, w = t >> 6, l = t & 63;
  const int lr = l >> 2, lk = (l & 3) * 8;   // staging: row-in-chunk, k-elem offset
  const int fr = l & 15, fk = (l >> 4) * 8;  // fragment: row-in-16tile, k offset

  const bf16* aG0 = Ab + (long)(m0 + w * 16 + lr) * p.lda + lk;
  const bf16* aG1 = aG0 + (long)64 * p.lda;
  const bf16* bG0 = Bb + (long)(n0 + w * 16 + lr) * p.ldb + lk;
  const bf16* bG1 = bG0 + (long)64 * p.ldb;
  bf16* aL0 = &As[w * 16 * 32];
  bf16* aL1 = &As[(w + 4) * 16 * 32];
  bf16* bL0 = &Bs[w * 16 * 32];
  bf16* bL1 = &Bs[(w + 4) * 16 * 32];
  const int wr = (NTILE == 128) ? (w >> 1) * 64 : w * 32;
  const int wc = (NTILE == 128) ? (w & 1) * 64 : 0;

  floatx4 zero4 = {0.f, 0.f, 0.f, 0.f};
  floatx4 acc[MI][4];
#pragma unroll
  for (int i = 0; i < MI; i++)
#pragma unroll
    for (int j = 0; j < 4; j++) acc[i][j] = zero4;

  for (int k0 = 0; k0 < p.K; k0 += 32) {
    lds_load16(aL0, aG0 + k0);
    lds_load16(aL1, aG1 + k0);
    lds_load16(bL0, bG0 + k0);
    if (NTILE == 128) lds_load16(bL1, bG1 + k0);
    __syncthreads();
    short8 af[MI], bfv[4];
#pragma unroll
    for (int i = 0; i < MI; i++)
      af[i] = *(const short8*)&As[(wr + i * 16 + fr) * 32 + fk];
#pragma unroll
    for (int j = 0; j < 4; j++)
      bfv[j] = *(const short8*)&Bs[(wc + j * 16 + fr) * 32 + fk];
#pragma unroll
    for (int i = 0; i < MI; i++)
#pragma unroll
      for (int j = 0; j < 4; j++)
        acc[i][j] = __builtin_amdgcn_mfma_f32_16x16x32_bf16(af[i], bfv[j], acc[i][j], 0, 0, 0);
    __syncthreads();
  }

  // epilogue: D[row][col], col = lane&15, row = (lane>>4)*4 + r  [m89-verified layout]
  const int cl = l & 15, rq = (l >> 4) * 4;
  const long cfBase = (long)imgA * p.sCfImg + (long)h * p.sCfH;
  const long cbBase = (long)imgA * p.sCbImg + (long)h * p.sCbH;
  const long chBase = (long)imgA * p.sChImg + (long)h * p.sChH;
#pragma unroll
  for (int j = 0; j < 4; j++) {
    const int col = n0 + wc + j * 16 + cl;
    if (col >= p.N) continue;
    const float bv = p.bias ? p.bias[col] : 0.f;
    const bool vcol = p.Cv && (col >= p.vColOfs);
    float cs = 0.f, cs2 = 0.f;
#pragma unroll
    for (int i = 0; i < MI; i++) {
      float vr[4];
#pragma unroll
      for (int r = 0; r < 4; r++) {
        const int row = m0 + wr + i * 16 + rq + r;
        float val = acc[i][j][r] * p.scale + bv;
        if (p.resid) val += p.resid[cfBase + (long)row * p.ldcf + col];
        if (p.Cf) p.Cf[cfBase + (long)row * p.ldcf + col] = val;
        if (p.Cb && !vcol) p.Cb[cbBase + (long)row * p.ldcb + col] = __float2bfloat16(val);
        if (p.Ch) p.Ch[chBase + (long)row * p.ldch + col] = __float2half(val);
        if (p.statsOut) { cs += val; cs2 += val * val; }
        vr[r] = val;
      }
      if (vcol) {  // transposed side-output: vchan[img][ch][tok], 4 rows -> one 8B store
        const int row0 = m0 + wr + i * 16 + rq;
        const int img = row0 >> 10, tok = row0 & 1023;
        const int ch = col - p.vColOfs;
        shortx4 pk;
#pragma unroll
        for (int r = 0; r < 4; r++) {
          bf16 bb = __float2bfloat16(vr[r]);
          pk[r] = *reinterpret_cast<short*>(&bb);
        }
        *(shortx4*)(p.Cv + (long)img * 524288 + (long)ch * 1024 + tok) = pk;
      }
    }
    if (p.statsOut) {  // block-local 128-row column sums -> 1 atomic pair / col / block
      cs += __shfl_xor(cs, 16); cs += __shfl_xor(cs, 32);
      cs2 += __shfl_xor(cs2, 16); cs2 += __shfl_xor(cs2, 32);
      if (l < 16) {
        const int img = m0 >> 10;
        atomicAdd(&p.statsOut[img * 2048 + col], cs);
        atomicAdd(&p.statsOut[img * 2048 + 1024 + col], cs2);
      }
    }
  }
}

// ---------------- fused flash attention (QBLK=64, 4 blocks/CU) ----------------
// r6: Q-tile 128->64 doubles resident blocks (2->4 per CU): halves the serial
// softmax chain per block, better VALU/MFMA overlap. LDS 32KB/block.
__global__ __launch_bounds__(256, 4)
void attn_fused(const bf16* __restrict__ QKV, const bf16* __restrict__ vchan,
                bf16* __restrict__ Yb, int cross) {
  __shared__ __align__(16) bf16 Qs[64 * 64];
  __shared__ __align__(16) bf16 Ks[64 * 64];
  __shared__ __align__(16) bf16 Vs[64 * 64];
  __shared__ __align__(16) bf16 Ps[64 * 64];
  const int z = blockIdx.z;
  const int img = z >> 3, h = z & 7;
  const int imgB = img ^ cross;
  const int q0 = blockIdx.x * 64;
  const int t = threadIdx.x, w = t >> 6, l = t & 63;
  const int g = l >> 4, fr = l & 15;
  const int wr = w * 16;

  {  // stage Q tile [64 rows][64 d], swizzled
    const bf16* src = QKV + ((long)(img * 1024 + q0)) * 1536 + h * 64;
#pragma unroll
    for (int k = 0; k < 2; k++) {
      const int chunk = t + k * 256;  // 0..511 = 64 rows x 8 chunks
      const int row = chunk >> 3, c16 = chunk & 7;
      const short8 vd = *(const short8*)(src + (long)row * 1536 + c16 * 8);
      *(short8*)((char*)Qs + row * 128 + ((c16 * 16) ^ ((row & 7) << 4))) = vd;
    }
  }
  __syncthreads();

  short8 qf[2];
#pragma unroll
  for (int ks = 0; ks < 2; ks++) {
    const int row = wr + fr;
    qf[ks] = *(const short8*)((const char*)Qs + row * 128 +
                              ((ks * 64 + g * 16) ^ ((row & 7) << 4)));
  }

  floatx4 zero4 = {0.f, 0.f, 0.f, 0.f};
  floatx4 Oa[4];
  float m_run[4], l_run[4];
#pragma unroll
  for (int r = 0; r < 4; r++) { m_run[r] = -3.0e38f; l_run[r] = 0.f; }
#pragma unroll
  for (int jd = 0; jd < 4; jd++) Oa[jd] = zero4;

  const bf16* ksrc0 = QKV + ((long)(imgB * 1024)) * 1536 + 512 + h * 64;
  const bf16* vsrc0 = vchan + (long)imgB * 524288 + (long)(h * 64) * 1024;

  for (int kv = 0; kv < 16; kv++) {
    const int kv0 = kv * 64;
#pragma unroll
    for (int k = 0; k < 2; k++) {
      const int ch = t + k * 256;
      const int row = ch >> 3, c16 = ch & 7;
      const short8 vd = *(const short8*)(ksrc0 + (long)(kv0 + row) * 1536 + c16 * 8);
      *(short8*)((char*)Ks + row * 128 + ((c16 * 16) ^ ((row & 7) << 4))) = vd;
    }
#pragma unroll
    for (int k = 0; k < 2; k++) {
      const int ch = t + k * 256;
      const int row = ch >> 3, c16 = ch & 7;  // row = d channel
      const short8 vd = *(const short8*)(vsrc0 + (long)row * 1024 + kv0 + c16 * 8);
      *(short8*)((char*)Vs + row * 128 + ((c16 * 16) ^ ((row & 7) << 4))) = vd;
    }
    __syncthreads();

    // S = Q K^T
    floatx4 sa[4];
#pragma unroll
    for (int j = 0; j < 4; j++) {
      sa[j] = zero4;
      const int row = j * 16 + fr;
      const short8 bk0 = *(const short8*)((const char*)Ks + row * 128 +
                                          ((g * 16) ^ ((row & 7) << 4)));
      const short8 bk1 = *(const short8*)((const char*)Ks + row * 128 +
                                          ((64 + g * 16) ^ ((row & 7) << 4)));
      sa[j] = __builtin_amdgcn_mfma_f32_16x16x32_bf16(qf[0], bk0, sa[j], 0, 0, 0);
      sa[j] = __builtin_amdgcn_mfma_f32_16x16x32_bf16(qf[1], bk1, sa[j], 0, 0, 0);
    }

    // online softmax (rows owned per r across 16-lane col groups)
#pragma unroll
    for (int r = 0; r < 4; r++) {
      float mx = -3.0e38f;
#pragma unroll
      for (int j = 0; j < 4; j++) {
        sa[j][r] *= 0.125f;
        mx = fmaxf(mx, sa[j][r]);
      }
#pragma unroll
      for (int o = 1; o < 16; o <<= 1) mx = fmaxf(mx, __shfl_xor(mx, o));
      const float mnew = fmaxf(m_run[r], mx);
      const float corr = __expf(m_run[r] - mnew);
      m_run[r] = mnew;
      float ps = 0.f;
#pragma unroll
      for (int j = 0; j < 4; j++) {
        const float pv = __expf(sa[j][r] - mnew);
        sa[j][r] = pv;
        ps += pv;
      }
#pragma unroll
      for (int o = 1; o < 16; o <<= 1) ps += __shfl_xor(ps, o);
      l_run[r] = l_run[r] * corr + ps;
#pragma unroll
      for (int jd = 0; jd < 4; jd++) Oa[jd][r] *= corr;
    }

    // P -> LDS (wave-local rows; swizzled scatter)
#pragma unroll
    for (int j = 0; j < 4; j++)
#pragma unroll
      for (int r = 0; r < 4; r++) {
        const int row = wr + g * 4 + r;
        const int colB = j * 32 + fr * 2;
        *(bf16*)((char*)Ps + row * 128 + (colB ^ ((row & 7) << 4))) =
            __float2bfloat16(sa[j][r]);
      }

    // O += P V
    short8 pf[2];
#pragma unroll
    for (int ks = 0; ks < 2; ks++) {
      const int row = wr + fr;
      pf[ks] = *(const short8*)((const char*)Ps + row * 128 +
                                ((ks * 64 + g * 16) ^ ((row & 7) << 4)));
    }
#pragma unroll
    for (int jd = 0; jd < 4; jd++) {
      const int row = jd * 16 + fr;  // d channel
      const short8 vf0 = *(const short8*)((const char*)Vs + row * 128 +
                                          ((g * 16) ^ ((row & 7) << 4)));
      const short8 vf1 = *(const short8*)((const char*)Vs + row * 128 +
                                          ((64 + g * 16) ^ ((row & 7) << 4)));
      Oa[jd] = __builtin_amdgcn_mfma_f32_16x16x32_bf16(pf[0], vf0, Oa[jd], 0, 0, 0);
      Oa[jd] = __builtin_amdgcn_mfma_f32_16x16x32_bf16(pf[1], vf1, Oa[jd], 0, 0, 0);
    }
    __syncthreads();  // protect Ks/Vs/Ps before next-iter staging
  }

  // epilogue: O /= l, write Yb[img][token][512 + h*64 + d]
#pragma unroll
  for (int r = 0; r < 4; r++) {
    const float inv = 1.f / l_run[r];
    const int qrow = q0 + wr + g * 4 + r;
    bf16* dst = Yb + ((long)img * 1024 + qrow) * 1024 + 512 + h * 64;
#pragma unroll
    for (int jd = 0; jd < 4; jd++)
      dst[jd * 16 + fr] = __float2bfloat16(Oa[jd][r] * inv);
  }
}

// ---------------- elementwise / helper kernels ----------------
__global__ __launch_bounds__(256)
void cvt_f2b(const float* __restrict__ in, bf16* __restrict__ out, long n) {
  long i = (long)blockIdx.x * 256 + threadIdx.x;
  const long stride = (long)gridDim.x * 256;
  for (; i < n; i += stride) out[i] = __float2bfloat16(in[i]);
}

// upfront: bf16 conversions for the Wm->W1 fold.
__global__ __launch_bounds__(256)
void cvt_prep(const float* __restrict__ W1, const float* __restrict__ Wm,
              bf16* __restrict__ w1r, bf16* __restrict__ wmT) {
  const long i = (long)blockIdx.x * 256 + threadIdx.x;
  if (i < 6291456L) {
    const int lay = (int)(i >> 19);
    const long r = i & 524287;
    const int o = (int)(r >> 9), k = (int)(r & 511);
    w1r[i] = __float2bfloat16(W1[(long)lay * 1048576 + (long)o * 1024 + 512 + k]);
  } else if (i < 9437184L) {
    const long j = i - 6291456L;
    const int lay = (int)(j >> 18);
    const long r = j & 262143;
    const int c = (int)(r >> 9), ii = (int)(r & 511);
    wmT[j] = __float2bfloat16(Wm[(long)lay * 262144 + (long)ii * 512 + (c & 63) * 8 + (c >> 6)]);
  }
}

// upfront: bc[l][o] = b1[l][o] + sum_i W1[l][o][512+i]*bm[l][i]  (wave per output)
__global__ __launch_bounds__(256)
void bc_calc(const float* __restrict__ W1, const float* __restrict__ bm,
             const float* __restrict__ b1, float* __restrict__ bc) {
  const int w = threadIdx.x >> 6, l = threadIdx.x & 63;
  const int og = blockIdx.x * 4 + w;  // 0..12287
  const int lay = og >> 10, o = og & 1023;
  const float* wrow = W1 + (long)lay * 1048576 + (long)o * 1024 + 512;
  const float* bmr = bm + lay * 512;
  float s = 0.f;
#pragma unroll
  for (int j = 0; j < 8; j++) s += wrow[l + 64 * j] * bmr[l + 64 * j];
#pragma unroll
  for (int o2 = 32; o2 >= 1; o2 >>= 1) s += __shfl_xor(s, o2);
  if (l == 0) bc[og] = b1[og] + s;
}

// per-layer weight conversion (4.5 MB rotating):
// [0:768K) wqkv | [768K:1.75M) w1merged = [W1left | Wc] | [1.75M:2.25M) w2
__global__ __launch_bounds__(256)
void cvt_layer(const float* __restrict__ Wq, const float* __restrict__ Wk,
               const float* __restrict__ Wv, const float* __restrict__ W1,
               const float* __restrict__ W2, const bf16* __restrict__ wcAll,
               const float* __restrict__ bq, const float* __restrict__ bk,
               const float* __restrict__ bv,
               int layer, bf16* __restrict__ out, float* __restrict__ bqkv) {
  const long i = (long)blockIdx.x * 256 + threadIdx.x;
  if (i >= 2359296L + 1536) return;
  if (i >= 2359296L) {
    const int j = (int)(i - 2359296L);
    float b;
    if (j < 512) b = bq[layer * 512 + j];
    else if (j < 1024) b = bk[layer * 512 + j - 512];
    else b = bv[layer * 512 + j - 1024];
    bqkv[j] = b;
    return;
  }
  if (i < 786432) {
    float v;
    if (i < 262144) v = Wq[(long)layer * 262144 + i];
    else if (i < 524288) v = Wk[(long)layer * 262144 + i - 262144];
    else v = Wv[(long)layer * 262144 + i - 524288];
    out[i] = __float2bfloat16(v);
  } else if (i < 1835008) {
    const long j = i - 786432;
    const int o = (int)(j >> 10), k = (int)(j & 1023);
    if (k < 512)
      out[i] = __float2bfloat16(W1[(long)layer * 1048576 + (long)o * 1024 + k]);
    else
      out[i] = wcAll[(long)layer * 524288 + (long)o * 512 + (k - 512)];
  } else {
    const long j = i - 1835008;
    out[i] = __float2bfloat16(W2[(long)layer * 524288 + j]);
  }
}

__global__ __launch_bounds__(256)
void init_x(const float* __restrict__ d0, const float* __restrict__ d1,
            float* __restrict__ Xf, bf16* __restrict__ Yb) {
  long i = (long)blockIdx.x * 256 + threadIdx.x;
  const long stride = (long)gridDim.x * 256;
  const long n = 8L * 1024 * 512;
  for (; i < n; i += stride) {
    const int d = (int)(i & 511);
    const long nn = i >> 9;  // img*1024 + row
    const int img = (int)(nn >> 10);
    const int row = (int)(nn & 1023);
    const int b = img >> 1, s = img & 1;
    const float v = (s ? d1 : d0)[((long)b * 1024 + row) * 512 + d];
    Xf[i] = v;
    Yb[(nn << 10) + d] = __float2bfloat16(v);
  }
}

__global__ __launch_bounds__(256)
void in_apply(const float* __restrict__ T1, const float* __restrict__ stats,
              bf16* __restrict__ Z) {
  long i = (long)blockIdx.x * 256 + threadIdx.x;
  const long stride = (long)gridDim.x * 256;
  for (; i < 8L * 1024 * 1024; i += stride) {
    const int c = (int)(i & 1023);
    const int img = (int)(i >> 20);
    const float mean = stats[img * 2048 + c] * (1.f / 1024.f);
    const float var = fmaxf(stats[img * 2048 + 1024 + c] * (1.f / 1024.f) - mean * mean, 0.f);
    const float zz = (T1[i] - mean) * rsqrtf(var + 1e-5f);
    Z[i] = __float2bfloat16(fmaxf(zz, 0.f));
  }
}

// fp32 coupling -> fp16 copy + fp16 transpose, with bin rows/cols filled inline
__global__ __launch_bounds__(256)
void coup_to_fp16(float* __restrict__ io, const float* __restrict__ alpha,
                  __half* __restrict__ outN, __half* __restrict__ outT) {
  __shared__ float tile[32][33];
  const float a = *alpha;
  const int b = blockIdx.z;
  const int x0 = blockIdx.x * 32, y0 = blockIdx.y * 32;
  const int lx = threadIdx.x & 31, ly = threadIdx.x >> 5;  // ly 0..7
#pragma unroll
  for (int i = 0; i < 4; i++) {
    const int y = ly + i * 8;
    if (y0 + y < 1025 && x0 + lx < 1025) {
      const long idx = ((long)b * 1025 + y0 + y) * 1025 + x0 + lx;
      const bool edge = (y0 + y == 1024) || (x0 + lx == 1024);
      float vv;
      if (edge) { vv = a; io[idx] = a; }
      else vv = io[idx];
      tile[y][lx] = vv;
      outN[idx] = __float2half(vv);
    }
  }
  __syncthreads();
#pragma unroll
  for (int i = 0; i < 4; i++) {
    const int y = ly + i * 8;
    if (x0 + y < 1025 && y0 + lx < 1025)
      outT[((long)b * 1025 + x0 + y) * 1025 + y0 + lx] = __float2half(tile[lx][y]);
  }
}

// -------- persistent Sinkhorn (r9 structure: per-lane spin on tagged u64 entries) ----
#define SK_BLOCKS 256

#define SK_ROUND(CREG, CLAST, XREG, XLAST, SRC, DST)                            \
  {                                                                             \
    u64t pr;                                                                    \
    while ((unsigned)((pr = __hip_atomic_load(&(SRC)[t], __ATOMIC_RELAXED,      \
                                              __HIP_MEMORY_SCOPE_AGENT)) >>    \
                      32) != tag)                                               \
      __builtin_amdgcn_s_sleep(1);                                              \
    sv[t] = __uint_as_float((unsigned)pr);                                      \
    if (t == 0) {                                                               \
      u64t qr;                                                                  \
      while ((unsigned)((qr = __hip_atomic_load(&(SRC)[1024], __ATOMIC_RELAXED, \
                                                __HIP_MEMORY_SCOPE_AGENT)) >>  \
                        32) != tag)                                             \
        __builtin_amdgcn_s_sleep(1);                                            \
      sv[1024] = __uint_as_float((unsigned)qr);                                 \
    }                                                                           \
    __syncthreads();                                                            \
    float M = (l == 0) ? ((CLAST) + sv[1024]) : -3.0e38f;                       \
    const float extra = M;                                                      \
    float x[16];                                                                \
    _Pragma("unroll") for (int i = 0; i < 16; i++) {                            \
      x[i] = (CREG)[i] + sv[l + 64 * i];                                        \
      M = fmaxf(M, x[i]);                                                       \
    }                                                                           \
    _Pragma("unroll") for (int o = 32; o >= 1; o >>= 1)                         \
        M = fmaxf(M, __shfl_xor(M, o));                                         \
    float S = (l == 0) ? __expf(extra - M) : 0.f;                               \
    _Pragma("unroll") for (int i = 0; i < 16; i++) S += __expf(x[i] - M);       \
    _Pragma("unroll") for (int o = 32; o >= 1; o >>= 1) S += __shfl_xor(S, o);  \
    if (l == 0) {                                                               \
      const float val = norm - (M + __logf(S));                                 \
      const u64t pk = ((u64t)(tag + 1) << 32) | (u64t)__float_as_uint(val);     \
      __hip_atomic_store(&(DST)[lw], pk, __ATOMIC_RELAXED,                      \
                         __HIP_MEMORY_SCOPE_AGENT);                             \
    }                                                                           \
    if (xtra) {                                                                 \
      float M2 = (l == 0) ? ((XLAST) + sv[1024]) : -3.0e38f;                    \
      const float e2 = M2;                                                      \
      float y[16];                                                              \
      _Pragma("unroll") for (int i = 0; i < 16; i++) {                          \
        y[i] = (XREG)[i] + sv[l + 64 * i];                                      \
        M2 = fmaxf(M2, y[i]);                                                   \
      }                                                                         \
      _Pragma("unroll") for (int o = 32; o >= 1; o >>= 1)                       \
          M2 = fmaxf(M2, __shfl_xor(M2, o));                                    \
      float S2 = (l == 0) ? __expf(e2 - M2) : 0.f;                              \
      _Pragma("unroll") for (int i = 0; i < 16; i++) S2 += __expf(y[i] - M2);   \
      _Pragma("unroll") for (int o = 32; o >= 1; o >>= 1)                       \
          S2 += __shfl_xor(S2, o);                                              \
      if (l == 0) {                                                             \
        const float v2 = (logN + norm) - (M2 + __logf(S2));                     \
        const u64t pk2 = ((u64t)(tag + 1) << 32) | (u64t)__float_as_uint(v2);   \
        __hip_atomic_store(&(DST)[1024], pk2, __ATOMIC_RELAXED,                 \
                           __HIP_MEMORY_SCOPE_AGENT);                           \
      }                                                                         \
    }                                                                           \
    tag++;                                                                      \
    __syncthreads();                                                            \
  }

__global__ __launch_bounds__(1024)
void sinkhorn_pers(const __half* __restrict__ C, const __half* __restrict__ CT,
                   u64t* __restrict__ u, u64t* __restrict__ v,
                   float norm, float logN, int iters) {
  __shared__ float sv[1025];
  const int t = threadIdx.x;
  const int w = t >> 6, l = t & 63;
  const int b = blockIdx.x >> 6;   // batch 0..3
  const int kb = blockIdx.x & 63;  // block within batch
  const int lw = kb * 16 + w;      // wave's row within batch: 0..1023
  const __half* Cb = C + (long)b * 1050625;
  const __half* CTb = CT + (long)b * 1050625;
  u64t* ub = u + b * 1025;
  u64t* vb = v + b * 1025;

  float cr[16], cc[16];
  float clC, clT;
  {
    const __half* rc = Cb + (long)lw * 1025;
    const __half* rt = CTb + (long)lw * 1025;
#pragma unroll
    for (int i = 0; i < 16; i++) {
      cr[i] = __half2float(rc[l + 64 * i]);
      cc[i] = __half2float(rt[l + 64 * i]);
    }
    clC = (l == 0) ? __half2float(rc[1024]) : 0.f;
    clT = (l == 0) ? __half2float(rt[1024]) : 0.f;
  }
  const bool xtra = (lw == 0);
  float xrC[16], xrT[16], xlC = 0.f, xlT = 0.f;
  if (xtra) {
    const __half* rc = Cb + (long)1024 * 1025;
    const __half* rt = CTb + (long)1024 * 1025;
#pragma unroll
    for (int i = 0; i < 16; i++) {
      xrC[i] = __half2float(rc[l + 64 * i]);
      xrT[i] = __half2float(rt[l + 64 * i]);
    }
    if (l == 0) {
      xlC = __half2float(rc[1024]);
      xlT = __half2float(rt[1024]);
    }
  }

  unsigned tag = 0;
  for (int it = 0; it < iters; it++) {
    SK_ROUND(cr, clC, xrC, xlC, vb, ub);
    SK_ROUND(cc, clT, xrT, xlT, ub, vb);
  }
}

__global__ __launch_bounds__(256)
void ot_final(float* __restrict__ C, const u64t* __restrict__ u,
              const u64t* __restrict__ v, float norm) {
  long i = (long)blockIdx.x * 256 + threadIdx.x;
  if (i >= 4L * 1025 * 1025) return;
  const int b = (int)(i / 1050625);
  const long r = i - (long)b * 1050625;
  const int n = (int)(r / 1025);
  const int m = (int)(r - (long)n * 1025);
  const float uu = __uint_as_float((unsigned)u[b * 1025 + n]);
  const float vv = __uint_as_float((unsigned)v[b * 1025 + m]);
  C[i] += uu + vv - norm;
}

// ---------------- host ----------------
extern "C" void kernel_launch(void* const* d_in, const int* in_sizes, int n_in,
                              void* d_out, int out_size, void* d_ws, size_t ws_size,
                              hipStream_t stream) {
  (void)in_sizes; (void)n_in; (void)out_size; (void)ws_size;
  const float* descs0 = (const float*)d_in[0];
  const float* descs1 = (const float*)d_in[1];
  const float* Wq = (const float*)d_in[2];
  const float* bq = (const float*)d_in[3];
  const float* Wk = (const float*)d_in[4];
  const float* bk = (const float*)d_in[5];
  const float* Wv = (const float*)d_in[6];
  const float* bvv = (const float*)d_in[7];
  const float* Wm = (const float*)d_in[8];
  const float* bm = (const float*)d_in[9];
  const float* W1 = (const float*)d_in[10];
  const float* b1 = (const float*)d_in[11];
  const float* W2 = (const float*)d_in[12];
  const float* b2 = (const float*)d_in[13];
  const float* Wf = (const float*)d_in[14];
  const float* bff = (const float*)d_in[15];
  const float* alpha = (const float*)d_in[16];

  char* ws = (char*)d_ws;
  size_t off = 0;
  auto alloc = [&](size_t bytes) -> void* {
    off = (off + 255) & ~(size_t)255;
    void* p = ws + off;
    off += bytes;
    return p;
  };

  bf16* wL = (bf16*)alloc(2359296L * 2);           // rotating per-layer weights (4.5 MB)
  float* bqkv = (float*)alloc(1536 * 4);
  bf16* WfB = (bf16*)alloc(512L * 512 * 2);
  bf16* wcAll = (bf16*)alloc(12L * 1024 * 512 * 2);  // folded W1R@Wm' (12 MB)
  float* bcAll = (float*)alloc(12L * 1024 * 4);      // folded bias
  float* Xf = (float*)alloc(8L * 1024 * 512 * 4);  // fp32 residual stream
  bf16* Yb = (bf16*)alloc(8L * 1024 * 1024 * 2);   // [img][n][1024]: 0:512 x, 512:1024 attnO
  bf16* QKVb = (bf16*)alloc(8L * 1024 * 1536 * 2); // [token][1536] q|k (v goes to vchan)
  bf16* vchan = (bf16*)alloc(8L * 1024 * 512 * 2); // [img][512ch][1024tok]
  char* SCR = (char*)alloc(50331648);              // 48 MB: prep tmp / T1+Zb / Ch+CTh+mproj
  float* stats = (float*)alloc(12L * 16384 * 4);   // per-layer IN stats
  u64t* u = (u64t*)alloc(4L * 1025 * 8);           // (tag<<32 | f32) pairs
  u64t* v = (u64t*)alloc(4L * 1025 * 8);

  bf16* wqkv = wL;                  // [1536][512]
  bf16* w1m = wL + 786432;          // [1024][1024] merged [W1left | Wc]
  bf16* w2 = wL + 1835008;          // [512][1024]
  float* T1 = (float*)SCR;                 // 32 MB
  bf16* Zb = (bf16*)(SCR + 33554432);      // 16 MB
  bf16* w1rTmp = (bf16*)SCR;               // prep: 12 MB (pre-layer-loop only)
  bf16* wmTTmp = (bf16*)(SCR + 12582912);  // prep: 6 MB
  __half* Ch = (__half*)SCR;               // 8.4 MB fp16 couplings (post-layers)
  __half* CTh = (__half*)(SCR + 8405248);  // 8.4 MB fp16 transposed
  bf16* mproj = (bf16*)(SCR + 33554432);   // 8 MB (post-layers)
  float* coup = (float*)d_out;

  cvt_f2b<<<512, 256, 0, stream>>>(Wf, WfB, 512L * 512);
  init_x<<<4096, 256, 0, stream>>>(descs0, descs1, Xf, Yb);
  // zero all 12 layers' stats slices once
  hipMemsetAsync(stats, 0, 12L * 16384 * 4, stream);

  auto gemm = [&](int ntile, const bf16* A, const bf16* B, int M, int N, int K,
                  int lda, int ldb, long sAimg, long sAh, long sBimg, long sBh,
                  int Z, int ZH, int cross, float scale, const float* bias,
                  float* Cf, int ldcf, long sCfImg, long sCfH,
                  bf16* Cb, int ldcb, long sCbImg, long sCbH,
                  __half* Ch_, int ldch, long sChImg, long sChH,
                  const float* resid, bf16* Cv, int vColOfs, float* statsOut) {
    GemmP p;
    p.A = A; p.B = B; p.M = M; p.N = N; p.K = K; p.lda = lda; p.ldb = ldb;
    p.sAimg = sAimg; p.sAh = sAh; p.sBimg = sBimg; p.sBh = sBh;
    p.ZH = ZH; p.cross = cross; p.scale = scale; p.bias = bias;
    p.Cf = Cf; p.ldcf = ldcf; p.sCfImg = sCfImg; p.sCfH = sCfH;
    p.Cb = Cb; p.ldcb = ldcb; p.sCbImg = sCbImg; p.sCbH = sCbH;
    p.Ch = Ch_; p.ldch = ldch; p.sChImg = sChImg; p.sChH = sChH;
    p.resid = resid; p.Cv = Cv; p.vColOfs = vColOfs; p.statsOut = statsOut;
    dim3 g((unsigned)((N + ntile - 1) / ntile), (unsigned)((M + 127) / 128), (unsigned)Z);
    if (ntile == 128) gemm_bt<128><<<g, 256, 0, stream>>>(p);
    else gemm_bt<64><<<g, 256, 0, stream>>>(p);
  };

  // ---- upfront fold: Wc[l] = W1R[l] @ wm'[l]  (batched Z=12), bc = b1 + W1R@bm ----
  cvt_prep<<<36864, 256, 0, stream>>>(W1, Wm, w1rTmp, wmTTmp);
  bc_calc<<<3072, 256, 0, stream>>>(W1, bm, b1, bcAll);
  gemm(128, w1rTmp, wmTTmp, 1024, 512, 512, 512, 512, 524288, 0, 262144, 0,
       12, 1, 0, 1.f, nullptr,
       nullptr, 0, 0, 0, wcAll, 512, 524288, 0, nullptr, 0, 0, 0,
       nullptr, nullptr, 0, nullptr);

  for (int i = 0; i < 12; i++) {
    const int cross = i & 1;  // NAMES = self,cross,self,...
    cvt_layer<<<9222, 256, 0, stream>>>(Wq, Wk, Wv, W1, W2, wcAll, bq, bk, bvv, i, wL, bqkv);

    // fused QKV: [8192,1536] = Yb[:, :512] x Wqkv^T; v-cols transposed into vchan
    gemm(128, Yb, wqkv, 8192, 1536, 512, 1024, 512, 0, 0, 0, 0, 1, 1, 0, 1.f, bqkv,
         nullptr, 0, 0, 0, QKVb, 1536, 0, 0, nullptr, 0, 0, 0,
         nullptr, vchan, 1024, nullptr);
    // fused flash attention -> Yb[:, 512:1024] (O in head-major channel order)
    attn_fused<<<dim3(16, 1, 64), 256, 0, stream>>>(QKVb, vchan, Yb, cross);

    // T1 = [W1L | Wc] x [x; O] + bc; instance-norm stats fused into epilogue
    gemm(128, Yb, w1m, 8192, 1024, 1024, 1024, 1024, 0, 0, 0, 0, 1, 1, 0, 1.f,
         bcAll + i * 1024,
         T1, 1024, 0, 0, nullptr, 0, 0, 0, nullptr, 0, 0, 0,
         nullptr, nullptr, 0, stats + (long)i * 16384);
    in_apply<<<8192, 256, 0, stream>>>(T1, stats + (long)i * 16384, Zb);
    // x += W2 z + b2 : fp32 residual into Xf, bf16 mirror into Yb[:, :512]
    gemm(128, Zb, w2, 8192, 512, 1024, 1024, 1024, 0, 0, 0, 0, 1, 1, 0, 1.f, b2 + i * 512,
         Xf, 512, 0, 0, Yb, 1024, 0, 0, nullptr, 0, 0, 0,
         Xf, nullptr, 0, nullptr);
  }

  // final projection + score matrix into d_out
  gemm(128, Yb, WfB, 8192, 512, 512, 1024, 512, 0, 0, 0, 0, 1, 1, 0, 1.f, bff,
       nullptr, 0, 0, 0, mproj, 512, 0, 0, nullptr, 0, 0, 0,
       nullptr, nullptr, 0, nullptr);
  gemm(128, mproj, mproj + 524288, 1024, 1024, 512, 512, 512,
       1048576, 0, 1048576, 0, 4, 1, 0,
       0.044194173824159216f, nullptr,
       coup, 1025, 1050625, 0, nullptr, 0, 0, 0, nullptr, 0, 0, 0,
       nullptr, nullptr, 0, nullptr);
  coup_to_fp16<<<dim3(33, 33, 4), 256, 0, stream>>>(coup, alpha, Ch, CTh);

  hipMemsetAsync(u, 0, 4L * 1025 * 8, stream);
  hipMemsetAsync(v, 0, 4L * 1025 * 8, stream);
  const float NORM = -logf(2048.f);
  const float LOGN = logf(1024.f);
  int iters = 100;
  void* args[] = {(void*)&Ch, (void*)&CTh, (void*)&u, (void*)&v,
                  (void*)&NORM, (void*)&LOGN, (void*)&iters};
  hipLaunchCooperativeKernel((void*)sinkhorn_pers, dim3(SK_BLOCKS), dim3(1024), args, 0, stream);
  ot_final<<<16417, 256, 0, stream>>>(coup, u, v, NORM);
}

// Round 9
// 2932.994 us; speedup vs baseline: 1.4961x; 1.0849x over previous
//
#include <hip/hip_runtime.h>
#include <hip/hip_bf16.h>
#include <hip/hip_fp16.h>
#include <cmath>

using bf16 = __hip_bfloat16;
typedef __attribute__((ext_vector_type(8))) short short8;
typedef __attribute__((ext_vector_type(4))) short shortx4;
typedef __attribute__((ext_vector_type(4))) float floatx4;
typedef unsigned long long u64t;

__device__ __forceinline__ void lds_load16(void* lds, const void* g) {
  __builtin_amdgcn_global_load_lds(
      (const __attribute__((address_space(1))) void*)g,
      (__attribute__((address_space(3))) void*)lds, 16, 0, 0);
}

// ---------------- generic BT GEMM: C[M][N] = scale*(A[M][K] x B[N][K]^T) + bias ----------
// Extras: Cv/vColOfs = transposed bf16 side-output for cols>=vColOfs (replaces
// transpose_2b); statsOut = per-(img,col) sum/sumsq atomics (replaces in_stats).
struct GemmP {
  const bf16* A; const bf16* B;
  int M, N, K, lda, ldb;
  long sAimg, sAh, sBimg, sBh;
  int ZH, cross;
  float scale;
  const float* bias;
  float* Cf; int ldcf; long sCfImg, sCfH;
  bf16* Cb; int ldcb; long sCbImg, sCbH;
  __half* Ch; int ldch; long sChImg, sChH;
  const float* resid;  // fp32, same indexing as Cf
  bf16* Cv; int vColOfs;
  float* statsOut;
};

template <int NTILE>  // 128: 4 waves x (64x64); 64: 4 waves x (32x64)
__global__ __launch_bounds__(256, 2)
void gemm_bt(GemmP p) {
  __shared__ __align__(16) bf16 As[128 * 32];
  __shared__ __align__(16) bf16 Bs[NTILE * 32];
  constexpr int MI = (NTILE == 128) ? 4 : 2;
  const int z = blockIdx.z;
  const int imgA = z / p.ZH;
  const int h = z - imgA * p.ZH;
  const int imgB = imgA ^ p.cross;
  const bf16* Ab = p.A + (long)imgA * p.sAimg + (long)h * p.sAh;
  const bf16* Bb = p.B + (long)imgB * p.sBimg + (long)h * p.sBh;

  // XCD-contiguous bijective remap (m157/m204): consecutive tiles (sharing A/B
  // panels) land on the SAME XCD's private L2. Only for z==1 grids, nwg%8==0.
  int bx = blockIdx.x, by = blockIdx.y;
  if (gridDim.z == 1) {
    const unsigned nwg = gridDim.x * gridDim.y;
    if ((nwg & 7u) == 0) {
      const unsigned id = blockIdx.y * gridDim.x + blockIdx.x;
      const unsigned nid = (id & 7u) * (nwg >> 3) + (id >> 3);
      bx = nid % gridDim.x;
      by = nid / gridDim.x;
    }
  }
  const int m0 = by * 128, n0 = bx * NTILE;
  const int t = threadIdx.x, w = t >> 6, l = t & 63;
  const int lr = l >> 2, lk = (l & 3) * 8;   // staging: row-in-chunk, k-elem offset
  const int fr = l & 15, fk = (l >> 4) * 8;  // fragment: row-in-16tile, k offset

  const bf16* aG0 = Ab + (long)(m0 + w * 16 + lr) * p.lda + lk;
  const bf16* aG1 = aG0 + (long)64 * p.lda;
  const bf16* bG0 = Bb + (long)(n0 + w * 16 + lr) * p.ldb + lk;
  const bf16* bG1 = bG0 + (long)64 * p.ldb;
  bf16* aL0 = &As[w * 16 * 32];
  bf16* aL1 = &As[(w + 4) * 16 * 32];
  bf16* bL0 = &Bs[w * 16 * 32];
  bf16* bL1 = &Bs[(w + 4) * 16 * 32];
  const int wr = (NTILE == 128) ? (w >> 1) * 64 : w * 32;
  const int wc = (NTILE == 128) ? (w & 1) * 64 : 0;

  floatx4 zero4 = {0.f, 0.f, 0.f, 0.f};
  floatx4 acc[MI][4];
#pragma unroll
  for (int i = 0; i < MI; i++)
#pragma unroll
    for (int j = 0; j < 4; j++) acc[i][j] = zero4;

  for (int k0 = 0; k0 < p.K; k0 += 32) {
    lds_load16(aL0, aG0 + k0);
    lds_load16(aL1, aG1 + k0);
    lds_load16(bL0, bG0 + k0);
    if (NTILE == 128) lds_load16(bL1, bG1 + k0);
    __syncthreads();
    short8 af[MI], bfv[4];
#pragma unroll
    for (int i = 0; i < MI; i++)
      af[i] = *(const short8*)&As[(wr + i * 16 + fr) * 32 + fk];
#pragma unroll
    for (int j = 0; j < 4; j++)
      bfv[j] = *(const short8*)&Bs[(wc + j * 16 + fr) * 32 + fk];
#pragma unroll
    for (int i = 0; i < MI; i++)
#pragma unroll
      for (int j = 0; j < 4; j++)
        acc[i][j] = __builtin_amdgcn_mfma_f32_16x16x32_bf16(af[i], bfv[j], acc[i][j], 0, 0, 0);
    __syncthreads();
  }

  // epilogue: D[row][col], col = lane&15, row = (lane>>4)*4 + r  [m89-verified layout]
  const int cl = l & 15, rq = (l >> 4) * 4;
  const long cfBase = (long)imgA * p.sCfImg + (long)h * p.sCfH;
  const long cbBase = (long)imgA * p.sCbImg + (long)h * p.sCbH;
  const long chBase = (long)imgA * p.sChImg + (long)h * p.sChH;
#pragma unroll
  for (int j = 0; j < 4; j++) {
    const int col = n0 + wc + j * 16 + cl;
    if (col >= p.N) continue;
    const float bv = p.bias ? p.bias[col] : 0.f;
    const bool vcol = p.Cv && (col >= p.vColOfs);
    float cs = 0.f, cs2 = 0.f;
#pragma unroll
    for (int i = 0; i < MI; i++) {
      float vr[4];
#pragma unroll
      for (int r = 0; r < 4; r++) {
        const int row = m0 + wr + i * 16 + rq + r;
        float val = acc[i][j][r] * p.scale + bv;
        if (p.resid) val += p.resid[cfBase + (long)row * p.ldcf + col];
        if (p.Cf) p.Cf[cfBase + (long)row * p.ldcf + col] = val;
        if (p.Cb && !vcol) p.Cb[cbBase + (long)row * p.ldcb + col] = __float2bfloat16(val);
        if (p.Ch) p.Ch[chBase + (long)row * p.ldch + col] = __float2half(val);
        if (p.statsOut) { cs += val; cs2 += val * val; }
        vr[r] = val;
      }
      if (vcol) {  // transposed side-output: vchan[img][ch][tok], 4 rows -> one 8B store
        const int row0 = m0 + wr + i * 16 + rq;
        const int img = row0 >> 10, tok = row0 & 1023;
        const int ch = col - p.vColOfs;
        shortx4 pk;
#pragma unroll
        for (int r = 0; r < 4; r++) {
          bf16 bb = __float2bfloat16(vr[r]);
          pk[r] = *reinterpret_cast<short*>(&bb);
        }
        *(shortx4*)(p.Cv + (long)img * 524288 + (long)ch * 1024 + tok) = pk;
      }
    }
    if (p.statsOut) {  // block-local 128-row column sums -> 1 atomic pair / col / block
      cs += __shfl_xor(cs, 16); cs += __shfl_xor(cs, 32);
      cs2 += __shfl_xor(cs2, 16); cs2 += __shfl_xor(cs2, 32);
      if (l < 16) {
        const int img = m0 >> 10;
        atomicAdd(&p.statsOut[img * 2048 + col], cs);
        atomicAdd(&p.statsOut[img * 2048 + 1024 + col], cs2);
      }
    }
  }
}

// ---------------- fused flash attention (QBLK=64, 4 blocks/CU) ----------------
__global__ __launch_bounds__(256, 4)
void attn_fused(const bf16* __restrict__ QKV, const bf16* __restrict__ vchan,
                bf16* __restrict__ Yb, int cross) {
  __shared__ __align__(16) bf16 Qs[64 * 64];
  __shared__ __align__(16) bf16 Ks[64 * 64];
  __shared__ __align__(16) bf16 Vs[64 * 64];
  __shared__ __align__(16) bf16 Ps[64 * 64];
  const int z = blockIdx.z;
  const int img = z >> 3, h = z & 7;
  const int imgB = img ^ cross;
  const int q0 = blockIdx.x * 64;
  const int t = threadIdx.x, w = t >> 6, l = t & 63;
  const int g = l >> 4, fr = l & 15;
  const int wr = w * 16;

  {  // stage Q tile [64 rows][64 d], swizzled
    const bf16* src = QKV + ((long)(img * 1024 + q0)) * 1536 + h * 64;
#pragma unroll
    for (int k = 0; k < 2; k++) {
      const int chunk = t + k * 256;  // 0..511 = 64 rows x 8 chunks
      const int row = chunk >> 3, c16 = chunk & 7;
      const short8 vd = *(const short8*)(src + (long)row * 1536 + c16 * 8);
      *(short8*)((char*)Qs + row * 128 + ((c16 * 16) ^ ((row & 7) << 4))) = vd;
    }
  }
  __syncthreads();

  short8 qf[2];
#pragma unroll
  for (int ks = 0; ks < 2; ks++) {
    const int row = wr + fr;
    qf[ks] = *(const short8*)((const char*)Qs + row * 128 +
                              ((ks * 64 + g * 16) ^ ((row & 7) << 4)));
  }

  floatx4 zero4 = {0.f, 0.f, 0.f, 0.f};
  floatx4 Oa[4];
  float m_run[4], l_run[4];
#pragma unroll
  for (int r = 0; r < 4; r++) { m_run[r] = -3.0e38f; l_run[r] = 0.f; }
#pragma unroll
  for (int jd = 0; jd < 4; jd++) Oa[jd] = zero4;

  const bf16* ksrc0 = QKV + ((long)(imgB * 1024)) * 1536 + 512 + h * 64;
  const bf16* vsrc0 = vchan + (long)imgB * 524288 + (long)(h * 64) * 1024;

  for (int kv = 0; kv < 16; kv++) {
    const int kv0 = kv * 64;
#pragma unroll
    for (int k = 0; k < 2; k++) {
      const int ch = t + k * 256;
      const int row = ch >> 3, c16 = ch & 7;
      const short8 vd = *(const short8*)(ksrc0 + (long)(kv0 + row) * 1536 + c16 * 8);
      *(short8*)((char*)Ks + row * 128 + ((c16 * 16) ^ ((row & 7) << 4))) = vd;
    }
#pragma unroll
    for (int k = 0; k < 2; k++) {
      const int ch = t + k * 256;
      const int row = ch >> 3, c16 = ch & 7;  // row = d channel
      const short8 vd = *(const short8*)(vsrc0 + (long)row * 1024 + kv0 + c16 * 8);
      *(short8*)((char*)Vs + row * 128 + ((c16 * 16) ^ ((row & 7) << 4))) = vd;
    }
    __syncthreads();

    // S = Q K^T
    floatx4 sa[4];
#pragma unroll
    for (int j = 0; j < 4; j++) {
      sa[j] = zero4;
      const int row = j * 16 + fr;
      const short8 bk0 = *(const short8*)((const char*)Ks + row * 128 +
                                          ((g * 16) ^ ((row & 7) << 4)));
      const short8 bk1 = *(const short8*)((const char*)Ks + row * 128 +
                                          ((64 + g * 16) ^ ((row & 7) << 4)));
      sa[j] = __builtin_amdgcn_mfma_f32_16x16x32_bf16(qf[0], bk0, sa[j], 0, 0, 0);
      sa[j] = __builtin_amdgcn_mfma_f32_16x16x32_bf16(qf[1], bk1, sa[j], 0, 0, 0);
    }

    // online softmax (rows owned per r across 16-lane col groups)
#pragma unroll
    for (int r = 0; r < 4; r++) {
      float mx = -3.0e38f;
#pragma unroll
      for (int j = 0; j < 4; j++) {
        sa[j][r] *= 0.125f;
        mx = fmaxf(mx, sa[j][r]);
      }
#pragma unroll
      for (int o = 1; o < 16; o <<= 1) mx = fmaxf(mx, __shfl_xor(mx, o));
      const float mnew = fmaxf(m_run[r], mx);
      const float corr = __expf(m_run[r] - mnew);
      m_run[r] = mnew;
      float ps = 0.f;
#pragma unroll
      for (int j = 0; j < 4; j++) {
        const float pv = __expf(sa[j][r] - mnew);
        sa[j][r] = pv;
        ps += pv;
      }
#pragma unroll
      for (int o = 1; o < 16; o <<= 1) ps += __shfl_xor(ps, o);
      l_run[r] = l_run[r] * corr + ps;
#pragma unroll
      for (int jd = 0; jd < 4; jd++) Oa[jd][r] *= corr;
    }

    // P -> LDS (wave-local rows; swizzled scatter)
#pragma unroll
    for (int j = 0; j < 4; j++)
#pragma unroll
      for (int r = 0; r < 4; r++) {
        const int row = wr + g * 4 + r;
        const int colB = j * 32 + fr * 2;
        *(bf16*)((char*)Ps + row * 128 + (colB ^ ((row & 7) << 4))) =
            __float2bfloat16(sa[j][r]);
      }

    // O += P V
    short8 pf[2];
#pragma unroll
    for (int ks = 0; ks < 2; ks++) {
      const int row = wr + fr;
      pf[ks] = *(const short8*)((const char*)Ps + row * 128 +
                                ((ks * 64 + g * 16) ^ ((row & 7) << 4)));
    }
#pragma unroll
    for (int jd = 0; jd < 4; jd++) {
      const int row = jd * 16 + fr;  // d channel
      const short8 vf0 = *(const short8*)((const char*)Vs + row * 128 +
                                          ((g * 16) ^ ((row & 7) << 4)));
      const short8 vf1 = *(const short8*)((const char*)Vs + row * 128 +
                                          ((64 + g * 16) ^ ((row & 7) << 4)));
      Oa[jd] = __builtin_amdgcn_mfma_f32_16x16x32_bf16(pf[0], vf0, Oa[jd], 0, 0, 0);
      Oa[jd] = __builtin_amdgcn_mfma_f32_16x16x32_bf16(pf[1], vf1, Oa[jd], 0, 0, 0);
    }
    __syncthreads();  // protect Ks/Vs/Ps before next-iter staging
  }

  // epilogue: O /= l, write Yb[img][token][512 + h*64 + d]
#pragma unroll
  for (int r = 0; r < 4; r++) {
    const float inv = 1.f / l_run[r];
    const int qrow = q0 + wr + g * 4 + r;
    bf16* dst = Yb + ((long)img * 1024 + qrow) * 1024 + 512 + h * 64;
#pragma unroll
    for (int jd = 0; jd < 4; jd++)
      dst[jd * 16 + fr] = __float2bfloat16(Oa[jd][r] * inv);
  }
}

// ---------------- elementwise / helper kernels ----------------
__global__ __launch_bounds__(256)
void cvt_f2b(const float* __restrict__ in, bf16* __restrict__ out, long n) {
  long i = (long)blockIdx.x * 256 + threadIdx.x;
  const long stride = (long)gridDim.x * 256;
  for (; i < n; i += stride) out[i] = __float2bfloat16(in[i]);
}

// upfront: bf16 conversions for the Wm->W1 fold.
__global__ __launch_bounds__(256)
void cvt_prep(const float* __restrict__ W1, const float* __restrict__ Wm,
              bf16* __restrict__ w1r, bf16* __restrict__ wmT) {
  const long i = (long)blockIdx.x * 256 + threadIdx.x;
  if (i < 6291456L) {
    const int lay = (int)(i >> 19);
    const long r = i & 524287;
    const int o = (int)(r >> 9), k = (int)(r & 511);
    w1r[i] = __float2bfloat16(W1[(long)lay * 1048576 + (long)o * 1024 + 512 + k]);
  } else if (i < 9437184L) {
    const long j = i - 6291456L;
    const int lay = (int)(j >> 18);
    const long r = j & 262143;
    const int c = (int)(r >> 9), ii = (int)(r & 511);
    wmT[j] = __float2bfloat16(Wm[(long)lay * 262144 + (long)ii * 512 + (c & 63) * 8 + (c >> 6)]);
  }
}

// upfront: bc[l][o] = b1[l][o] + sum_i W1[l][o][512+i]*bm[l][i]  (wave per output)
__global__ __launch_bounds__(256)
void bc_calc(const float* __restrict__ W1, const float* __restrict__ bm,
             const float* __restrict__ b1, float* __restrict__ bc) {
  const int w = threadIdx.x >> 6, l = threadIdx.x & 63;
  const int og = blockIdx.x * 4 + w;  // 0..12287
  const int lay = og >> 10, o = og & 1023;
  const float* wrow = W1 + (long)lay * 1048576 + (long)o * 1024 + 512;
  const float* bmr = bm + lay * 512;
  float s = 0.f;
#pragma unroll
  for (int j = 0; j < 8; j++) s += wrow[l + 64 * j] * bmr[l + 64 * j];
#pragma unroll
  for (int o2 = 32; o2 >= 1; o2 >>= 1) s += __shfl_xor(s, o2);
  if (l == 0) bc[og] = b1[og] + s;
}

// per-layer weight conversion (4.5 MB rotating):
// [0:768K) wqkv | [768K:1.75M) w1merged = [W1left | Wc] | [1.75M:2.25M) w2
__global__ __launch_bounds__(256)
void cvt_layer(const float* __restrict__ Wq, const float* __restrict__ Wk,
               const float* __restrict__ Wv, const float* __restrict__ W1,
               const float* __restrict__ W2, const bf16* __restrict__ wcAll,
               const float* __restrict__ bq, const float* __restrict__ bk,
               const float* __restrict__ bv,
               int layer, bf16* __restrict__ out, float* __restrict__ bqkv) {
  const long i = (long)blockIdx.x * 256 + threadIdx.x;
  if (i >= 2359296L + 1536) return;
  if (i >= 2359296L) {
    const int j = (int)(i - 2359296L);
    float b;
    if (j < 512) b = bq[layer * 512 + j];
    else if (j < 1024) b = bk[layer * 512 + j - 512];
    else b = bv[layer * 512 + j - 1024];
    bqkv[j] = b;
    return;
  }
  if (i < 786432) {
    float v;
    if (i < 262144) v = Wq[(long)layer * 262144 + i];
    else if (i < 524288) v = Wk[(long)layer * 262144 + i - 262144];
    else v = Wv[(long)layer * 262144 + i - 524288];
    out[i] = __float2bfloat16(v);
  } else if (i < 1835008) {
    const long j = i - 786432;
    const int o = (int)(j >> 10), k = (int)(j & 1023);
    if (k < 512)
      out[i] = __float2bfloat16(W1[(long)layer * 1048576 + (long)o * 1024 + k]);
    else
      out[i] = wcAll[(long)layer * 524288 + (long)o * 512 + (k - 512)];
  } else {
    const long j = i - 1835008;
    out[i] = __float2bfloat16(W2[(long)layer * 524288 + j]);
  }
}

__global__ __launch_bounds__(256)
void init_x(const float* __restrict__ d0, const float* __restrict__ d1,
            float* __restrict__ Xf, bf16* __restrict__ Yb) {
  long i = (long)blockIdx.x * 256 + threadIdx.x;
  const long stride = (long)gridDim.x * 256;
  const long n = 8L * 1024 * 512;
  for (; i < n; i += stride) {
    const int d = (int)(i & 511);
    const long nn = i >> 9;  // img*1024 + row
    const int img = (int)(nn >> 10);
    const int row = (int)(nn & 1023);
    const int b = img >> 1, s = img & 1;
    const float v = (s ? d1 : d0)[((long)b * 1024 + row) * 512 + d];
    Xf[i] = v;
    Yb[(nn << 10) + d] = __float2bfloat16(v);
  }
}

// vectorized instance-norm apply: float4 loads, shortx4 store (G13)
__global__ __launch_bounds__(256)
void in_apply(const float* __restrict__ T1, const float* __restrict__ stats,
              bf16* __restrict__ Z) {
  long i = (long)blockIdx.x * 256 + threadIdx.x;  // float4 index
  const long stride = (long)gridDim.x * 256;
  for (; i < 2L * 1024 * 1024; i += stride) {
    const float4 tv = *(const float4*)(T1 + i * 4);
    const int c0 = (int)((i * 4) & 1023);
    const int img = (int)(i >> 18);
    const float* st = stats + img * 2048;
    float vv[4] = {tv.x, tv.y, tv.z, tv.w};
    shortx4 zo;
#pragma unroll
    for (int k = 0; k < 4; k++) {
      const int c = c0 + k;
      const float mean = st[c] * (1.f / 1024.f);
      const float var = fmaxf(st[1024 + c] * (1.f / 1024.f) - mean * mean, 0.f);
      const float zz = (vv[k] - mean) * rsqrtf(var + 1e-5f);
      bf16 bb = __float2bfloat16(fmaxf(zz, 0.f));
      zo[k] = *reinterpret_cast<short*>(&bb);
    }
    *(shortx4*)(Z + i * 4) = zo;
  }
}

// fp32 coupling -> fp16 copy + fp16 transpose, with bin rows/cols filled inline
__global__ __launch_bounds__(256)
void coup_to_fp16(float* __restrict__ io, const float* __restrict__ alpha,
                  __half* __restrict__ outN, __half* __restrict__ outT) {
  __shared__ float tile[32][33];
  const float a = *alpha;
  const int b = blockIdx.z;
  const int x0 = blockIdx.x * 32, y0 = blockIdx.y * 32;
  const int lx = threadIdx.x & 31, ly = threadIdx.x >> 5;  // ly 0..7
#pragma unroll
  for (int i = 0; i < 4; i++) {
    const int y = ly + i * 8;
    if (y0 + y < 1025 && x0 + lx < 1025) {
      const long idx = ((long)b * 1025 + y0 + y) * 1025 + x0 + lx;
      const bool edge = (y0 + y == 1024) || (x0 + lx == 1024);
      float vv;
      if (edge) { vv = a; io[idx] = a; }
      else vv = io[idx];
      tile[y][lx] = vv;
      outN[idx] = __float2half(vv);
    }
  }
  __syncthreads();
#pragma unroll
  for (int i = 0; i < 4; i++) {
    const int y = ly + i * 8;
    if (x0 + y < 1025 && y0 + lx < 1025)
      outT[((long)b * 1025 + x0 + y) * 1025 + y0 + lx] = __float2half(tile[lx][y]);
  }
}

// -------- persistent Sinkhorn (r9 structure: per-lane spin on tagged u64 entries) ----
#define SK_BLOCKS 256

#define SK_ROUND(CREG, CLAST, XREG, XLAST, SRC, DST)                            \
  {                                                                             \
    u64t pr;                                                                    \
    while ((unsigned)((pr = __hip_atomic_load(&(SRC)[t], __ATOMIC_RELAXED,      \
                                              __HIP_MEMORY_SCOPE_AGENT)) >>    \
                      32) != tag)                                               \
      __builtin_amdgcn_s_sleep(1);                                              \
    sv[t] = __uint_as_float((unsigned)pr);                                      \
    if (t == 0) {                                                               \
      u64t qr;                                                                  \
      while ((unsigned)((qr = __hip_atomic_load(&(SRC)[1024], __ATOMIC_RELAXED, \
                                                __HIP_MEMORY_SCOPE_AGENT)) >>  \
                        32) != tag)                                             \
        __builtin_amdgcn_s_sleep(1);                                            \
      sv[1024] = __uint_as_float((unsigned)qr);                                 \
    }                                                                           \
    __syncthreads();                                                            \
    float M = (l == 0) ? ((CLAST) + sv[1024]) : -3.0e38f;                       \
    const float extra = M;                                                      \
    float x[16];                                                                \
    _Pragma("unroll") for (int i = 0; i < 16; i++) {                            \
      x[i] = (CREG)[i] + sv[l + 64 * i];                                        \
      M = fmaxf(M, x[i]);                                                       \
    }                                                                           \
    _Pragma("unroll") for (int o = 32; o >= 1; o >>= 1)                         \
        M = fmaxf(M, __shfl_xor(M, o));                                         \
    float S = (l == 0) ? __expf(extra - M) : 0.f;                               \
    _Pragma("unroll") for (int i = 0; i < 16; i++) S += __expf(x[i] - M);       \
    _Pragma("unroll") for (int o = 32; o >= 1; o >>= 1) S += __shfl_xor(S, o);  \
    if (l == 0) {                                                               \
      const float val = norm - (M + __logf(S));                                 \
      const u64t pk = ((u64t)(tag + 1) << 32) | (u64t)__float_as_uint(val);     \
      __hip_atomic_store(&(DST)[lw], pk, __ATOMIC_RELAXED,                      \
                         __HIP_MEMORY_SCOPE_AGENT);                             \
    }                                                                           \
    if (xtra) {                                                                 \
      float M2 = (l == 0) ? ((XLAST) + sv[1024]) : -3.0e38f;                    \
      const float e2 = M2;                                                      \
      float y[16];                                                              \
      _Pragma("unroll") for (int i = 0; i < 16; i++) {                          \
        y[i] = (XREG)[i] + sv[l + 64 * i];                                      \
        M2 = fmaxf(M2, y[i]);                                                   \
      }                                                                         \
      _Pragma("unroll") for (int o = 32; o >= 1; o >>= 1)                       \
          M2 = fmaxf(M2, __shfl_xor(M2, o));                                    \
      float S2 = (l == 0) ? __expf(e2 - M2) : 0.f;                              \
      _Pragma("unroll") for (int i = 0; i < 16; i++) S2 += __expf(y[i] - M2);   \
      _Pragma("unroll") for (int o = 32; o >= 1; o >>= 1)                       \
          S2 += __shfl_xor(S2, o);                                              \
      if (l == 0) {                                                             \
        const float v2 = (logN + norm) - (M2 + __logf(S2));                     \
        const u64t pk2 = ((u64t)(tag + 1) << 32) | (u64t)__float_as_uint(v2);   \
        __hip_atomic_store(&(DST)[1024], pk2, __ATOMIC_RELAXED,                 \
                           __HIP_MEMORY_SCOPE_AGENT);                           \
      }                                                                         \
    }                                                                           \
    tag++;                                                                      \
    __syncthreads();                                                            \
  }

__global__ __launch_bounds__(1024)
void sinkhorn_pers(const __half* __restrict__ C, const __half* __restrict__ CT,
                   u64t* __restrict__ u, u64t* __restrict__ v,
                   float norm, float logN, int iters) {
  __shared__ float sv[1025];
  const int t = threadIdx.x;
  const int w = t >> 6, l = t & 63;
  const int b = blockIdx.x >> 6;   // batch 0..3
  const int kb = blockIdx.x & 63;  // block within batch
  const int lw = kb * 16 + w;      // wave's row within batch: 0..1023
  const __half* Cb = C + (long)b * 1050625;
  const __half* CTb = CT + (long)b * 1050625;
  u64t* ub = u + b * 1025;
  u64t* vb = v + b * 1025;

  float cr[16], cc[16];
  float clC, clT;
  {
    const __half* rc = Cb + (long)lw * 1025;
    const __half* rt = CTb + (long)lw * 1025;
#pragma unroll
    for (int i = 0; i < 16; i++) {
      cr[i] = __half2float(rc[l + 64 * i]);
      cc[i] = __half2float(rt[l + 64 * i]);
    }
    clC = (l == 0) ? __half2float(rc[1024]) : 0.f;
    clT = (l == 0) ? __half2float(rt[1024]) : 0.f;
  }
  const bool xtra = (lw == 0);
  float xrC[16], xrT[16], xlC = 0.f, xlT = 0.f;
  if (xtra) {
    const __half* rc = Cb + (long)1024 * 1025;
    const __half* rt = CTb + (long)1024 * 1025;
#pragma unroll
    for (int i = 0; i < 16; i++) {
      xrC[i] = __half2float(rc[l + 64 * i]);
      xrT[i] = __half2float(rt[l + 64 * i]);
    }
    if (l == 0) {
      xlC = __half2float(rc[1024]);
      xlT = __half2float(rt[1024]);
    }
  }

  unsigned tag = 0;
  for (int it = 0; it < iters; it++) {
    SK_ROUND(cr, clC, xrC, xlC, vb, ub);
    SK_ROUND(cc, clT, xrT, xlT, ub, vb);
  }
}

__global__ __launch_bounds__(256)
void ot_final(float* __restrict__ C, const u64t* __restrict__ u,
              const u64t* __restrict__ v, float norm) {
  long i = (long)blockIdx.x * 256 + threadIdx.x;
  if (i >= 4L * 1025 * 1025) return;
  const int b = (int)(i / 1050625);
  const long r = i - (long)b * 1050625;
  const int n = (int)(r / 1025);
  const int m = (int)(r - (long)n * 1025);
  const float uu = __uint_as_float((unsigned)u[b * 1025 + n]);
  const float vv = __uint_as_float((unsigned)v[b * 1025 + m]);
  C[i] += uu + vv - norm;
}

// ---------------- host ----------------
extern "C" void kernel_launch(void* const* d_in, const int* in_sizes, int n_in,
                              void* d_out, int out_size, void* d_ws, size_t ws_size,
                              hipStream_t stream) {
  (void)in_sizes; (void)n_in; (void)out_size; (void)ws_size;
  const float* descs0 = (const float*)d_in[0];
  const float* descs1 = (const float*)d_in[1];
  const float* Wq = (const float*)d_in[2];
  const float* bq = (const float*)d_in[3];
  const float* Wk = (const float*)d_in[4];
  const float* bk = (const float*)d_in[5];
  const float* Wv = (const float*)d_in[6];
  const float* bvv = (const float*)d_in[7];
  const float* Wm = (const float*)d_in[8];
  const float* bm = (const float*)d_in[9];
  const float* W1 = (const float*)d_in[10];
  const float* b1 = (const float*)d_in[11];
  const float* W2 = (const float*)d_in[12];
  const float* b2 = (const float*)d_in[13];
  const float* Wf = (const float*)d_in[14];
  const float* bff = (const float*)d_in[15];
  const float* alpha = (const float*)d_in[16];

  char* ws = (char*)d_ws;
  size_t off = 0;
  auto alloc = [&](size_t bytes) -> void* {
    off = (off + 255) & ~(size_t)255;
    void* p = ws + off;
    off += bytes;
    return p;
  };

  bf16* wL = (bf16*)alloc(2359296L * 2);           // rotating per-layer weights (4.5 MB)
  float* bqkv = (float*)alloc(1536 * 4);
  bf16* WfB = (bf16*)alloc(512L * 512 * 2);
  bf16* wcAll = (bf16*)alloc(12L * 1024 * 512 * 2);  // folded W1R@Wm' (12 MB)
  float* bcAll = (float*)alloc(12L * 1024 * 4);      // folded bias
  float* Xf = (float*)alloc(8L * 1024 * 512 * 4);  // fp32 residual stream
  bf16* Yb = (bf16*)alloc(8L * 1024 * 1024 * 2);   // [img][n][1024]: 0:512 x, 512:1024 attnO
  bf16* QKVb = (bf16*)alloc(8L * 1024 * 1536 * 2); // [token][1536] q|k (v goes to vchan)
  bf16* vchan = (bf16*)alloc(8L * 1024 * 512 * 2); // [img][512ch][1024tok]
  char* SCR = (char*)alloc(50331648);              // 48 MB: prep tmp / T1+Zb / Ch+CTh+mproj
  float* stats = (float*)alloc(12L * 16384 * 4);   // per-layer IN stats
  u64t* u = (u64t*)alloc(4L * 1025 * 8);           // (tag<<32 | f32) pairs
  u64t* v = (u64t*)alloc(4L * 1025 * 8);

  bf16* wqkv = wL;                  // [1536][512]
  bf16* w1m = wL + 786432;          // [1024][1024] merged [W1left | Wc]
  bf16* w2 = wL + 1835008;          // [512][1024]
  float* T1 = (float*)SCR;                 // 32 MB
  bf16* Zb = (bf16*)(SCR + 33554432);      // 16 MB
  bf16* w1rTmp = (bf16*)SCR;               // prep: 12 MB (pre-layer-loop only)
  bf16* wmTTmp = (bf16*)(SCR + 12582912);  // prep: 6 MB
  __half* Ch = (__half*)SCR;               // 8.4 MB fp16 couplings (post-layers)
  __half* CTh = (__half*)(SCR + 8405248);  // 8.4 MB fp16 transposed
  bf16* mproj = (bf16*)(SCR + 33554432);   // 8 MB (post-layers)
  float* coup = (float*)d_out;

  cvt_f2b<<<512, 256, 0, stream>>>(Wf, WfB, 512L * 512);
  init_x<<<4096, 256, 0, stream>>>(descs0, descs1, Xf, Yb);
  // zero all 12 layers' stats slices once
  hipMemsetAsync(stats, 0, 12L * 16384 * 4, stream);

  auto gemm = [&](int ntile, const bf16* A, const bf16* B, int M, int N, int K,
                  int lda, int ldb, long sAimg, long sAh, long sBimg, long sBh,
                  int Z, int ZH, int cross, float scale, const float* bias,
                  float* Cf, int ldcf, long sCfImg, long sCfH,
                  bf16* Cb, int ldcb, long sCbImg, long sCbH,
                  __half* Ch_, int ldch, long sChImg, long sChH,
                  const float* resid, bf16* Cv, int vColOfs, float* statsOut) {
    GemmP p;
    p.A = A; p.B = B; p.M = M; p.N = N; p.K = K; p.lda = lda; p.ldb = ldb;
    p.sAimg = sAimg; p.sAh = sAh; p.sBimg = sBimg; p.sBh = sBh;
    p.ZH = ZH; p.cross = cross; p.scale = scale; p.bias = bias;
    p.Cf = Cf; p.ldcf = ldcf; p.sCfImg = sCfImg; p.sCfH = sCfH;
    p.Cb = Cb; p.ldcb = ldcb; p.sCbImg = sCbImg; p.sCbH = sCbH;
    p.Ch = Ch_; p.ldch = ldch; p.sChImg = sChImg; p.sChH = sChH;
    p.resid = resid; p.Cv = Cv; p.vColOfs = vColOfs; p.statsOut = statsOut;
    dim3 g((unsigned)((N + ntile - 1) / ntile), (unsigned)((M + 127) / 128), (unsigned)Z);
    if (ntile == 128) gemm_bt<128><<<g, 256, 0, stream>>>(p);
    else gemm_bt<64><<<g, 256, 0, stream>>>(p);
  };

  // ---- upfront fold: Wc[l] = W1R[l] @ wm'[l]  (batched Z=12), bc = b1 + W1R@bm ----
  cvt_prep<<<36864, 256, 0, stream>>>(W1, Wm, w1rTmp, wmTTmp);
  bc_calc<<<3072, 256, 0, stream>>>(W1, bm, b1, bcAll);
  gemm(128, w1rTmp, wmTTmp, 1024, 512, 512, 512, 512, 524288, 0, 262144, 0,
       12, 1, 0, 1.f, nullptr,
       nullptr, 0, 0, 0, wcAll, 512, 524288, 0, nullptr, 0, 0, 0,
       nullptr, nullptr, 0, nullptr);

  for (int i = 0; i < 12; i++) {
    const int cross = i & 1;  // NAMES = self,cross,self,...
    cvt_layer<<<9222, 256, 0, stream>>>(Wq, Wk, Wv, W1, W2, wcAll, bq, bk, bvv, i, wL, bqkv);

    // fused QKV: [8192,1536] = Yb[:, :512] x Wqkv^T; v-cols transposed into vchan
    gemm(128, Yb, wqkv, 8192, 1536, 512, 1024, 512, 0, 0, 0, 0, 1, 1, 0, 1.f, bqkv,
         nullptr, 0, 0, 0, QKVb, 1536, 0, 0, nullptr, 0, 0, 0,
         nullptr, vchan, 1024, nullptr);
    // fused flash attention -> Yb[:, 512:1024] (O in head-major channel order)
    attn_fused<<<dim3(16, 1, 64), 256, 0, stream>>>(QKVb, vchan, Yb, cross);

    // T1 = [W1L | Wc] x [x; O] + bc; instance-norm stats fused into epilogue
    gemm(128, Yb, w1m, 8192, 1024, 1024, 1024, 1024, 0, 0, 0, 0, 1, 1, 0, 1.f,
         bcAll + i * 1024,
         T1, 1024, 0, 0, nullptr, 0, 0, 0, nullptr, 0, 0, 0,
         nullptr, nullptr, 0, stats + (long)i * 16384);
    in_apply<<<2048, 256, 0, stream>>>(T1, stats + (long)i * 16384, Zb);
    // x += W2 z + b2 (NTILE=64: 512 blocks -> 2 blocks/CU; was 256 -> 1/CU)
    gemm(64, Zb, w2, 8192, 512, 1024, 1024, 1024, 0, 0, 0, 0, 1, 1, 0, 1.f, b2 + i * 512,
         Xf, 512, 0, 0, Yb, 1024, 0, 0, nullptr, 0, 0, 0,
         Xf, nullptr, 0, nullptr);
  }

  // final projection + score matrix into d_out
  gemm(64, Yb, WfB, 8192, 512, 512, 1024, 512, 0, 0, 0, 0, 1, 1, 0, 1.f, bff,
       nullptr, 0, 0, 0, mproj, 512, 0, 0, nullptr, 0, 0, 0,
       nullptr, nullptr, 0, nullptr);
  gemm(128, mproj, mproj + 524288, 1024, 1024, 512, 512, 512,
       1048576, 0, 1048576, 0, 4, 1, 0,
       0.044194173824159216f, nullptr,
       coup, 1025, 1050625, 0, nullptr, 0, 0, 0, nullptr, 0, 0, 0,
       nullptr, nullptr, 0, nullptr);
  coup_to_fp16<<<dim3(33, 33, 4), 256, 0, stream>>>(coup, alpha, Ch, CTh);

  hipMemsetAsync(u, 0, 4L * 1025 * 8, stream);
  hipMemsetAsync(v, 0, 4L * 1025 * 8, stream);
  const float NORM = -logf(2048.f);
  const float LOGN = logf(1024.f);
  int iters = 100;
  void* args[] = {(void*)&Ch, (void*)&CTh, (void*)&u, (void*)&v,
                  (void*)&NORM, (void*)&LOGN, (void*)&iters};
  hipLaunchCooperativeKernel((void*)sinkhorn_pers, dim3(SK_BLOCKS), dim3(1024), args, 0, stream);
  ot_final<<<16417, 256, 0, stream>>>(coup, u, v, NORM);
}

// Round 11
// 2926.721 us; speedup vs baseline: 1.4993x; 1.0021x over previous
//
#include <hip/hip_runtime.h>
#include <hip/hip_bf16.h>
#include <hip/hip_fp16.h>
#include <cmath>

using bf16 = __hip_bfloat16;
typedef __attribute__((ext_vector_type(8))) short short8;
typedef __attribute__((ext_vector_type(4))) short shortx4;
typedef __attribute__((ext_vector_type(4))) float floatx4;
typedef unsigned long long u64t;

__device__ __forceinline__ void lds_load16(void* lds, const void* g) {
  __builtin_amdgcn_global_load_lds(
      (const __attribute__((address_space(1))) void*)g,
      (__attribute__((address_space(3))) void*)lds, 16, 0, 0);
}

// ---------------- generic BT GEMM: C[M][N] = scale*(A[M][K] x B[N][K]^T) + bias ----------
// Extras: Cv/vColOfs = transposed bf16 side-output for cols>=vColOfs (replaces
// transpose_2b); statsOut = per-(img,col) sum/sumsq atomics (replaces in_stats).
struct GemmP {
  const bf16* A; const bf16* B;
  int M, N, K, lda, ldb;
  long sAimg, sAh, sBimg, sBh;
  int ZH, cross;
  float scale;
  const float* bias;
  float* Cf; int ldcf; long sCfImg, sCfH;
  bf16* Cb; int ldcb; long sCbImg, sCbH;
  __half* Ch; int ldch; long sChImg, sChH;
  const float* resid;  // fp32, same indexing as Cf
  bf16* Cv; int vColOfs;
  float* statsOut;
};

template <int NTILE>  // 128: 4 waves x (64x64); 64: 4 waves x (32x64)
__global__ __launch_bounds__(256, 2)
void gemm_bt(GemmP p) {
  __shared__ __align__(16) bf16 As[128 * 32];
  __shared__ __align__(16) bf16 Bs[NTILE * 32];
  constexpr int MI = (NTILE == 128) ? 4 : 2;
  const int z = blockIdx.z;
  const int imgA = z / p.ZH;
  const int h = z - imgA * p.ZH;
  const int imgB = imgA ^ p.cross;
  const bf16* Ab = p.A + (long)imgA * p.sAimg + (long)h * p.sAh;
  const bf16* Bb = p.B + (long)imgB * p.sBimg + (long)h * p.sBh;

  // XCD-contiguous bijective remap (m157/m204): consecutive tiles (sharing A/B
  // panels) land on the SAME XCD's private L2. Only for z==1 grids, nwg%8==0.
  int bx = blockIdx.x, by = blockIdx.y;
  if (gridDim.z == 1) {
    const unsigned nwg = gridDim.x * gridDim.y;
    if ((nwg & 7u) == 0) {
      const unsigned id = blockIdx.y * gridDim.x + blockIdx.x;
      const unsigned nid = (id & 7u) * (nwg >> 3) + (id >> 3);
      bx = nid % gridDim.x;
      by = nid / gridDim.x;
    }
  }
  const int m0 = by * 128, n0 = bx * NTILE;
  const int t = threadIdx.x, w = t >> 6, l = t & 63;
  const int lr = l >> 2, lk = (l & 3) * 8;   // staging: row-in-chunk, k-elem offset
  const int fr = l & 15, fk = (l >> 4) * 8;  // fragment: row-in-16tile, k offset

  const bf16* aG0 = Ab + (long)(m0 + w * 16 + lr) * p.lda + lk;
  const bf16* aG1 = aG0 + (long)64 * p.lda;
  const bf16* bG0 = Bb + (long)(n0 + w * 16 + lr) * p.ldb + lk;
  const bf16* bG1 = bG0 + (long)64 * p.ldb;
  bf16* aL0 = &As[w * 16 * 32];
  bf16* aL1 = &As[(w + 4) * 16 * 32];
  bf16* bL0 = &Bs[w * 16 * 32];
  bf16* bL1 = &Bs[(w + 4) * 16 * 32];
  const int wr = (NTILE == 128) ? (w >> 1) * 64 : w * 32;
  const int wc = (NTILE == 128) ? (w & 1) * 64 : 0;

  floatx4 zero4 = {0.f, 0.f, 0.f, 0.f};
  floatx4 acc[MI][4];
#pragma unroll
  for (int i = 0; i < MI; i++)
#pragma unroll
    for (int j = 0; j < 4; j++) acc[i][j] = zero4;

  for (int k0 = 0; k0 < p.K; k0 += 32) {
    lds_load16(aL0, aG0 + k0);
    lds_load16(aL1, aG1 + k0);
    lds_load16(bL0, bG0 + k0);
    if (NTILE == 128) lds_load16(bL1, bG1 + k0);
    __syncthreads();
    short8 af[MI], bfv[4];
#pragma unroll
    for (int i = 0; i < MI; i++)
      af[i] = *(const short8*)&As[(wr + i * 16 + fr) * 32 + fk];
#pragma unroll
    for (int j = 0; j < 4; j++)
      bfv[j] = *(const short8*)&Bs[(wc + j * 16 + fr) * 32 + fk];
#pragma unroll
    for (int i = 0; i < MI; i++)
#pragma unroll
      for (int j = 0; j < 4; j++)
        acc[i][j] = __builtin_amdgcn_mfma_f32_16x16x32_bf16(af[i], bfv[j], acc[i][j], 0, 0, 0);
    __syncthreads();
  }

  // epilogue: D[row][col], col = lane&15, row = (lane>>4)*4 + r  [m89-verified layout]
  const int cl = l & 15, rq = (l >> 4) * 4;
  const long cfBase = (long)imgA * p.sCfImg + (long)h * p.sCfH;
  const long cbBase = (long)imgA * p.sCbImg + (long)h * p.sCbH;
  const long chBase = (long)imgA * p.sChImg + (long)h * p.sChH;
#pragma unroll
  for (int j = 0; j < 4; j++) {
    const int col = n0 + wc + j * 16 + cl;
    if (col >= p.N) continue;
    const float bv = p.bias ? p.bias[col] : 0.f;
    const bool vcol = p.Cv && (col >= p.vColOfs);
    float cs = 0.f, cs2 = 0.f;
#pragma unroll
    for (int i = 0; i < MI; i++) {
      float vr[4];
#pragma unroll
      for (int r = 0; r < 4; r++) {
        const int row = m0 + wr + i * 16 + rq + r;
        float val = acc[i][j][r] * p.scale + bv;
        if (p.resid) val += p.resid[cfBase + (long)row * p.ldcf + col];
        if (p.Cf) p.Cf[cfBase + (long)row * p.ldcf + col] = val;
        if (p.Cb && !vcol) p.Cb[cbBase + (long)row * p.ldcb + col] = __float2bfloat16(val);
        if (p.Ch) p.Ch[chBase + (long)row * p.ldch + col] = __float2half(val);
        if (p.statsOut) { cs += val; cs2 += val * val; }
        vr[r] = val;
      }
      if (vcol) {  // transposed side-output: vchan[img][ch][tok], 4 rows -> one 8B store
        const int row0 = m0 + wr + i * 16 + rq;
        const int img = row0 >> 10, tok = row0 & 1023;
        const int ch = col - p.vColOfs;
        shortx4 pk;
#pragma unroll
        for (int r = 0; r < 4; r++) {
          bf16 bb = __float2bfloat16(vr[r]);
          pk[r] = *reinterpret_cast<short*>(&bb);
        }
        *(shortx4*)(p.Cv + (long)img * 524288 + (long)ch * 1024 + tok) = pk;
      }
    }
    if (p.statsOut) {  // block-local 128-row column sums -> 1 atomic pair / col / block
      cs += __shfl_xor(cs, 16); cs += __shfl_xor(cs, 32);
      cs2 += __shfl_xor(cs2, 16); cs2 += __shfl_xor(cs2, 32);
      if (l < 16) {
        const int img = m0 >> 10;
        atomicAdd(&p.statsOut[img * 2048 + col], cs);
        atomicAdd(&p.statsOut[img * 2048 + 1024 + col], cs2);
      }
    }
  }
}

// ---------------- fused flash attention (QBLK=64, 4 blocks/CU) ----------------
__global__ __launch_bounds__(256, 4)
void attn_fused(const bf16* __restrict__ QKV, const bf16* __restrict__ vchan,
                bf16* __restrict__ Yb, int cross) {
  __shared__ __align__(16) bf16 Qs[64 * 64];
  __shared__ __align__(16) bf16 Ks[64 * 64];
  __shared__ __align__(16) bf16 Vs[64 * 64];
  __shared__ __align__(16) bf16 Ps[64 * 64];
  const int z = blockIdx.z;
  const int img = z >> 3, h = z & 7;
  const int imgB = img ^ cross;
  const int q0 = blockIdx.x * 64;
  const int t = threadIdx.x, w = t >> 6, l = t & 63;
  const int g = l >> 4, fr = l & 15;
  const int wr = w * 16;

  {  // stage Q tile [64 rows][64 d], swizzled
    const bf16* src = QKV + ((long)(img * 1024 + q0)) * 1536 + h * 64;
#pragma unroll
    for (int k = 0; k < 2; k++) {
      const int chunk = t + k * 256;  // 0..511 = 64 rows x 8 chunks
      const int row = chunk >> 3, c16 = chunk & 7;
      const short8 vd = *(const short8*)(src + (long)row * 1536 + c16 * 8);
      *(short8*)((char*)Qs + row * 128 + ((c16 * 16) ^ ((row & 7) << 4))) = vd;
    }
  }
  __syncthreads();

  short8 qf[2];
#pragma unroll
  for (int ks = 0; ks < 2; ks++) {
    const int row = wr + fr;
    qf[ks] = *(const short8*)((const char*)Qs + row * 128 +
                              ((ks * 64 + g * 16) ^ ((row & 7) << 4)));
  }

  floatx4 zero4 = {0.f, 0.f, 0.f, 0.f};
  floatx4 Oa[4];
  float m_run[4], l_run[4];
#pragma unroll
  for (int r = 0; r < 4; r++) { m_run[r] = -3.0e38f; l_run[r] = 0.f; }
#pragma unroll
  for (int jd = 0; jd < 4; jd++) Oa[jd] = zero4;

  const bf16* ksrc0 = QKV + ((long)(imgB * 1024)) * 1536 + 512 + h * 64;
  const bf16* vsrc0 = vchan + (long)imgB * 524288 + (long)(h * 64) * 1024;

  for (int kv = 0; kv < 16; kv++) {
    const int kv0 = kv * 64;
#pragma unroll
    for (int k = 0; k < 2; k++) {
      const int ch = t + k * 256;
      const int row = ch >> 3, c16 = ch & 7;
      const short8 vd = *(const short8*)(ksrc0 + (long)(kv0 + row) * 1536 + c16 * 8);
      *(short8*)((char*)Ks + row * 128 + ((c16 * 16) ^ ((row & 7) << 4))) = vd;
    }
#pragma unroll
    for (int k = 0; k < 2; k++) {
      const int ch = t + k * 256;
      const int row = ch >> 3, c16 = ch & 7;  // row = d channel
      const short8 vd = *(const short8*)(vsrc0 + (long)row * 1024 + kv0 + c16 * 8);
      *(short8*)((char*)Vs + row * 128 + ((c16 * 16) ^ ((row & 7) << 4))) = vd;
    }
    __syncthreads();

    // S = Q K^T
    floatx4 sa[4];
#pragma unroll
    for (int j = 0; j < 4; j++) {
      sa[j] = zero4;
      const int row = j * 16 + fr;
      const short8 bk0 = *(const short8*)((const char*)Ks + row * 128 +
                                          ((g * 16) ^ ((row & 7) << 4)));
      const short8 bk1 = *(const short8*)((const char*)Ks + row * 128 +
                                          ((64 + g * 16) ^ ((row & 7) << 4)));
      sa[j] = __builtin_amdgcn_mfma_f32_16x16x32_bf16(qf[0], bk0, sa[j], 0, 0, 0);
      sa[j] = __builtin_amdgcn_mfma_f32_16x16x32_bf16(qf[1], bk1, sa[j], 0, 0, 0);
    }

    // online softmax (rows owned per r across 16-lane col groups)
#pragma unroll
    for (int r = 0; r < 4; r++) {
      float mx = -3.0e38f;
#pragma unroll
      for (int j = 0; j < 4; j++) {
        sa[j][r] *= 0.125f;
        mx = fmaxf(mx, sa[j][r]);
      }
#pragma unroll
      for (int o = 1; o < 16; o <<= 1) mx = fmaxf(mx, __shfl_xor(mx, o));
      const float mnew = fmaxf(m_run[r], mx);
      const float corr = __expf(m_run[r] - mnew);
      m_run[r] = mnew;
      float ps = 0.f;
#pragma unroll
      for (int j = 0; j < 4; j++) {
        const float pv = __expf(sa[j][r] - mnew);
        sa[j][r] = pv;
        ps += pv;
      }
#pragma unroll
      for (int o = 1; o < 16; o <<= 1) ps += __shfl_xor(ps, o);
      l_run[r] = l_run[r] * corr + ps;
#pragma unroll
      for (int jd = 0; jd < 4; jd++) Oa[jd][r] *= corr;
    }

    // P -> LDS (wave-local rows; swizzled scatter)
#pragma unroll
    for (int j = 0; j < 4; j++)
#pragma unroll
      for (int r = 0; r < 4; r++) {
        const int row = wr + g * 4 + r;
        const int colB = j * 32 + fr * 2;
        *(bf16*)((char*)Ps + row * 128 + (colB ^ ((row & 7) << 4))) =
            __float2bfloat16(sa[j][r]);
      }

    // O += P V
    short8 pf[2];
#pragma unroll
    for (int ks = 0; ks < 2; ks++) {
      const int row = wr + fr;
      pf[ks] = *(const short8*)((const char*)Ps + row * 128 +
                                ((ks * 64 + g * 16) ^ ((row & 7) << 4)));
    }
#pragma unroll
    for (int jd = 0; jd < 4; jd++) {
      const int row = jd * 16 + fr;  // d channel
      const short8 vf0 = *(const short8*)((const char*)Vs + row * 128 +
                                          ((g * 16) ^ ((row & 7) << 4)));
      const short8 vf1 = *(const short8*)((const char*)Vs + row * 128 +
                                          ((64 + g * 16) ^ ((row & 7) << 4)));
      Oa[jd] = __builtin_amdgcn_mfma_f32_16x16x32_bf16(pf[0], vf0, Oa[jd], 0, 0, 0);
      Oa[jd] = __builtin_amdgcn_mfma_f32_16x16x32_bf16(pf[1], vf1, Oa[jd], 0, 0, 0);
    }
    __syncthreads();  // protect Ks/Vs/Ps before next-iter staging
  }

  // epilogue: O /= l, write Yb[img][token][512 + h*64 + d]
#pragma unroll
  for (int r = 0; r < 4; r++) {
    const float inv = 1.f / l_run[r];
    const int qrow = q0 + wr + g * 4 + r;
    bf16* dst = Yb + ((long)img * 1024 + qrow) * 1024 + 512 + h * 64;
#pragma unroll
    for (int jd = 0; jd < 4; jd++)
      dst[jd * 16 + fr] = __float2bfloat16(Oa[jd][r] * inv);
  }
}

// ---------------- elementwise / helper kernels ----------------
__global__ __launch_bounds__(256)
void cvt_f2b(const float* __restrict__ in, bf16* __restrict__ out, long n) {
  long i = (long)blockIdx.x * 256 + threadIdx.x;
  const long stride = (long)gridDim.x * 256;
  for (; i < n; i += stride) out[i] = __float2bfloat16(in[i]);
}

// upfront: bf16 conversions for the Wm->W1 fold.
__global__ __launch_bounds__(256)
void cvt_prep(const float* __restrict__ W1, const float* __restrict__ Wm,
              bf16* __restrict__ w1r, bf16* __restrict__ wmT) {
  const long i = (long)blockIdx.x * 256 + threadIdx.x;
  if (i < 6291456L) {
    const int lay = (int)(i >> 19);
    const long r = i & 524287;
    const int o = (int)(r >> 9), k = (int)(r & 511);
    w1r[i] = __float2bfloat16(W1[(long)lay * 1048576 + (long)o * 1024 + 512 + k]);
  } else if (i < 9437184L) {
    const long j = i - 6291456L;
    const int lay = (int)(j >> 18);
    const long r = j & 262143;
    const int c = (int)(r >> 9), ii = (int)(r & 511);
    wmT[j] = __float2bfloat16(Wm[(long)lay * 262144 + (long)ii * 512 + (c & 63) * 8 + (c >> 6)]);
  }
}

// upfront: bc[l][o] = b1[l][o] + sum_i W1[l][o][512+i]*bm[l][i]  (wave per output)
__global__ __launch_bounds__(256)
void bc_calc(const float* __restrict__ W1, const float* __restrict__ bm,
             const float* __restrict__ b1, float* __restrict__ bc) {
  const int w = threadIdx.x >> 6, l = threadIdx.x & 63;
  const int og = blockIdx.x * 4 + w;  // 0..12287
  const int lay = og >> 10, o = og & 1023;
  const float* wrow = W1 + (long)lay * 1048576 + (long)o * 1024 + 512;
  const float* bmr = bm + lay * 512;
  float s = 0.f;
#pragma unroll
  for (int j = 0; j < 8; j++) s += wrow[l + 64 * j] * bmr[l + 64 * j];
#pragma unroll
  for (int o2 = 32; o2 >= 1; o2 >>= 1) s += __shfl_xor(s, o2);
  if (l == 0) bc[og] = b1[og] + s;
}

// per-layer weight conversion, float4-vectorized (G13):
// [0:768K) wqkv | [768K:1.75M) w1merged = [W1left | Wc] | [1.75M:2.25M) w2
__global__ __launch_bounds__(256)
void cvt_layer(const float* __restrict__ Wq, const float* __restrict__ Wk,
               const float* __restrict__ Wv, const float* __restrict__ W1,
               const float* __restrict__ W2, const bf16* __restrict__ wcAll,
               const float* __restrict__ bq, const float* __restrict__ bk,
               const float* __restrict__ bv,
               int layer, bf16* __restrict__ out, float* __restrict__ bqkv) {
  const long i = (long)blockIdx.x * 256 + threadIdx.x;
  if (i >= 589824) {  // 2359296/4 quads, then 1536 bias entries
    const int j = (int)(i - 589824);
    if (j < 1536) {
      float b;
      if (j < 512) b = bq[layer * 512 + j];
      else if (j < 1024) b = bk[layer * 512 + j - 512];
      else b = bv[layer * 512 + j - 1024];
      bqkv[j] = b;
    }
    return;
  }
  const long e = i * 4;
  float4 vs;
  if (e < 786432) {
    const int rgn = (int)(e >> 18);
    const long o = e & 262143;
    const float* W = (rgn == 0) ? Wq : (rgn == 1) ? Wk : Wv;
    vs = *(const float4*)(W + (long)layer * 262144 + o);
  } else if (e < 1835008) {
    const long j = e - 786432;
    const int o = (int)(j >> 10), k = (int)(j & 1023);
    if (k >= 512) {  // bf16 Wc: straight 8B copy
      *(shortx4*)(out + e) =
          *(const shortx4*)(wcAll + (long)layer * 524288 + (long)o * 512 + (k - 512));
      return;
    }
    vs = *(const float4*)(W1 + (long)layer * 1048576 + (long)o * 1024 + k);
  } else {
    vs = *(const float4*)(W2 + (long)layer * 524288 + (e - 1835008));
  }
  float vv[4] = {vs.x, vs.y, vs.z, vs.w};
  shortx4 pk;
#pragma unroll
  for (int k = 0; k < 4; k++) {
    bf16 bb = __float2bfloat16(vv[k]);
    pk[k] = *reinterpret_cast<short*>(&bb);
  }
  *(shortx4*)(out + e) = pk;
}

// float4-vectorized init (G13)
__global__ __launch_bounds__(256)
void init_x(const float* __restrict__ d0, const float* __restrict__ d1,
            float* __restrict__ Xf, bf16* __restrict__ Yb) {
  long i = (long)blockIdx.x * 256 + threadIdx.x;  // float4 index
  const long stride = (long)gridDim.x * 256;
  for (; i < 1048576; i += stride) {
    const int d4 = (int)(i & 127);
    const long nn = i >> 7;  // img*1024 + row
    const int img = (int)(nn >> 10);
    const int row = (int)(nn & 1023);
    const int b = img >> 1, s = img & 1;
    const float4 v = *(const float4*)((s ? d1 : d0) + ((long)b * 1024 + row) * 512 + d4 * 4);
    *(float4*)(Xf + i * 4) = v;
    float vv[4] = {v.x, v.y, v.z, v.w};
    shortx4 pk;
#pragma unroll
    for (int k = 0; k < 4; k++) {
      bf16 bb = __float2bfloat16(vv[k]);
      pk[k] = *reinterpret_cast<short*>(&bb);
    }
    *(shortx4*)(Yb + (nn << 10) + d4 * 4) = pk;
  }
}

// vectorized instance-norm apply: float4 loads, shortx4 store (G13)
__global__ __launch_bounds__(256)
void in_apply(const float* __restrict__ T1, const float* __restrict__ stats,
              bf16* __restrict__ Z) {
  long i = (long)blockIdx.x * 256 + threadIdx.x;  // float4 index
  const long stride = (long)gridDim.x * 256;
  for (; i < 2L * 1024 * 1024; i += stride) {
    const float4 tv = *(const float4*)(T1 + i * 4);
    const int c0 = (int)((i * 4) & 1023);
    const int img = (int)(i >> 18);
    const float* st = stats + img * 2048;
    float vv[4] = {tv.x, tv.y, tv.z, tv.w};
    shortx4 zo;
#pragma unroll
    for (int k = 0; k < 4; k++) {
      const int c = c0 + k;
      const float mean = st[c] * (1.f / 1024.f);
      const float var = fmaxf(st[1024 + c] * (1.f / 1024.f) - mean * mean, 0.f);
      const float zz = (vv[k] - mean) * rsqrtf(var + 1e-5f);
      bf16 bb = __float2bfloat16(fmaxf(zz, 0.f));
      zo[k] = *reinterpret_cast<short*>(&bb);
    }
    *(shortx4*)(Z + i * 4) = zo;
  }
}

// fp32 coupling -> fp16 copy + fp16 transpose, with bin rows/cols filled inline
__global__ __launch_bounds__(256)
void coup_to_fp16(float* __restrict__ io, const float* __restrict__ alpha,
                  __half* __restrict__ outN, __half* __restrict__ outT) {
  __shared__ float tile[32][33];
  const float a = *alpha;
  const int b = blockIdx.z;
  const int x0 = blockIdx.x * 32, y0 = blockIdx.y * 32;
  const int lx = threadIdx.x & 31, ly = threadIdx.x >> 5;  // ly 0..7
#pragma unroll
  for (int i = 0; i < 4; i++) {
    const int y = ly + i * 8;
    if (y0 + y < 1025 && x0 + lx < 1025) {
      const long idx = ((long)b * 1025 + y0 + y) * 1025 + x0 + lx;
      const bool edge = (y0 + y == 1024) || (x0 + lx == 1024);
      float vv;
      if (edge) { vv = a; io[idx] = a; }
      else vv = io[idx];
      tile[y][lx] = vv;
      outN[idx] = __float2half(vv);
    }
  }
  __syncthreads();
#pragma unroll
  for (int i = 0; i < 4; i++) {
    const int y = ly + i * 8;
    if (x0 + y < 1025 && y0 + lx < 1025)
      outT[((long)b * 1025 + x0 + y) * 1025 + y0 + lx] = __float2half(tile[lx][y]);
  }
}

// -------- persistent Sinkhorn (r8-PROVEN structure: 256 blocks, xtra wave,
// per-lane spin on tagged u64 entries). r9's 260-block variant failed
// (cooperative-launch capacity suspected); reverted byte-for-byte. --------
#define SK_BLOCKS 256

#define SK_ROUND(CREG, CLAST, XREG, XLAST, SRC, DST)                            \
  {                                                                             \
    u64t pr;                                                                    \
    while ((unsigned)((pr = __hip_atomic_load(&(SRC)[t], __ATOMIC_RELAXED,      \
                                              __HIP_MEMORY_SCOPE_AGENT)) >>    \
                      32) != tag)                                               \
      __builtin_amdgcn_s_sleep(1);                                              \
    sv[t] = __uint_as_float((unsigned)pr);                                      \
    if (t == 0) {                                                               \
      u64t qr;                                                                  \
      while ((unsigned)((qr = __hip_atomic_load(&(SRC)[1024], __ATOMIC_RELAXED, \
                                                __HIP_MEMORY_SCOPE_AGENT)) >>  \
                        32) != tag)                                             \
        __builtin_amdgcn_s_sleep(1);                                            \
      sv[1024] = __uint_as_float((unsigned)qr);                                 \
    }                                                                           \
    __syncthreads();                                                            \
    float M = (l == 0) ? ((CLAST) + sv[1024]) : -3.0e38f;                       \
    const float extra = M;                                                      \
    float x[16];                                                                \
    _Pragma("unroll") for (int i = 0; i < 16; i++) {                            \
      x[i] = (CREG)[i] + sv[l + 64 * i];                                        \
      M = fmaxf(M, x[i]);                                                       \
    }                                                                           \
    _Pragma("unroll") for (int o = 32; o >= 1; o >>= 1)                         \
        M = fmaxf(M, __shfl_xor(M, o));                                         \
    float S = (l == 0) ? __expf(extra - M) : 0.f;                               \
    _Pragma("unroll") for (int i = 0; i < 16; i++) S += __expf(x[i] - M);       \
    _Pragma("unroll") for (int o = 32; o >= 1; o >>= 1) S += __shfl_xor(S, o);  \
    if (l == 0) {                                                               \
      const float val = norm - (M + __logf(S));                                 \
      const u64t pk = ((u64t)(tag + 1) << 32) | (u64t)__float_as_uint(val);     \
      __hip_atomic_store(&(DST)[lw], pk, __ATOMIC_RELAXED,                      \
                         __HIP_MEMORY_SCOPE_AGENT);                             \
    }                                                                           \
    if (xtra) {                                                                 \
      float M2 = (l == 0) ? ((XLAST) + sv[1024]) : -3.0e38f;                    \
      const float e2 = M2;                                                      \
      float y[16];                                                              \
      _Pragma("unroll") for (int i = 0; i < 16; i++) {                          \
        y[i] = (XREG)[i] + sv[l + 64 * i];                                      \
        M2 = fmaxf(M2, y[i]);                                                   \
      }                                                                         \
      _Pragma("unroll") for (int o = 32; o >= 1; o >>= 1)                       \
          M2 = fmaxf(M2, __shfl_xor(M2, o));                                    \
      float S2 = (l == 0) ? __expf(e2 - M2) : 0.f;                              \
      _Pragma("unroll") for (int i = 0; i < 16; i++) S2 += __expf(y[i] - M2);   \
      _Pragma("unroll") for (int o = 32; o >= 1; o >>= 1)                       \
          S2 += __shfl_xor(S2, o);                                              \
      if (l == 0) {                                                             \
        const float v2 = (logN + norm) - (M2 + __logf(S2));                     \
        const u64t pk2 = ((u64t)(tag + 1) << 32) | (u64t)__float_as_uint(v2);   \
        __hip_atomic_store(&(DST)[1024], pk2, __ATOMIC_RELAXED,                 \
                           __HIP_MEMORY_SCOPE_AGENT);                           \
      }                                                                         \
    }                                                                           \
    tag++;                                                                      \
    __syncthreads();                                                            \
  }

__global__ __launch_bounds__(1024)
void sinkhorn_pers(const __half* __restrict__ C, const __half* __restrict__ CT,
                   u64t* __restrict__ u, u64t* __restrict__ v,
                   float norm, float logN, int iters) {
  __shared__ float sv[1025];
  const int t = threadIdx.x;
  const int w = t >> 6, l = t & 63;
  const int b = blockIdx.x >> 6;   // batch 0..3
  const int kb = blockIdx.x & 63;  // block within batch
  const int lw = kb * 16 + w;      // wave's row within batch: 0..1023
  const __half* Cb = C + (long)b * 1050625;
  const __half* CTb = CT + (long)b * 1050625;
  u64t* ub = u + b * 1025;
  u64t* vb = v + b * 1025;

  float cr[16], cc[16];
  float clC, clT;
  {
    const __half* rc = Cb + (long)lw * 1025;
    const __half* rt = CTb + (long)lw * 1025;
#pragma unroll
    for (int i = 0; i < 16; i++) {
      cr[i] = __half2float(rc[l + 64 * i]);
      cc[i] = __half2float(rt[l + 64 * i]);
    }
    clC = (l == 0) ? __half2float(rc[1024]) : 0.f;
    clT = (l == 0) ? __half2float(rt[1024]) : 0.f;
  }
  const bool xtra = (lw == 0);
  float xrC[16], xrT[16], xlC = 0.f, xlT = 0.f;
  if (xtra) {
    const __half* rc = Cb + (long)1024 * 1025;
    const __half* rt = CTb + (long)1024 * 1025;
#pragma unroll
    for (int i = 0; i < 16; i++) {
      xrC[i] = __half2float(rc[l + 64 * i]);
      xrT[i] = __half2float(rt[l + 64 * i]);
    }
    if (l == 0) {
      xlC = __half2float(rc[1024]);
      xlT = __half2float(rt[1024]);
    }
  }

  unsigned tag = 0;
  for (int it = 0; it < iters; it++) {
    SK_ROUND(cr, clC, xrC, xlC, vb, ub);
    SK_ROUND(cc, clT, xrT, xlT, ub, vb);
  }
}

__global__ __launch_bounds__(256)
void ot_final(float* __restrict__ C, const u64t* __restrict__ u,
              const u64t* __restrict__ v, float norm) {
  long i = (long)blockIdx.x * 256 + threadIdx.x;
  if (i >= 4L * 1025 * 1025) return;
  const int b = (int)(i / 1050625);
  const long r = i - (long)b * 1050625;
  const int n = (int)(r / 1025);
  const int m = (int)(r - (long)n * 1025);
  const float uu = __uint_as_float((unsigned)u[b * 1025 + n]);
  const float vv = __uint_as_float((unsigned)v[b * 1025 + m]);
  C[i] += uu + vv - norm;
}

// ---------------- host ----------------
extern "C" void kernel_launch(void* const* d_in, const int* in_sizes, int n_in,
                              void* d_out, int out_size, void* d_ws, size_t ws_size,
                              hipStream_t stream) {
  (void)in_sizes; (void)n_in; (void)out_size; (void)ws_size;
  const float* descs0 = (const float*)d_in[0];
  const float* descs1 = (const float*)d_in[1];
  const float* Wq = (const float*)d_in[2];
  const float* bq = (const float*)d_in[3];
  const float* Wk = (const float*)d_in[4];
  const float* bk = (const float*)d_in[5];
  const float* Wv = (const float*)d_in[6];
  const float* bvv = (const float*)d_in[7];
  const float* Wm = (const float*)d_in[8];
  const float* bm = (const float*)d_in[9];
  const float* W1 = (const float*)d_in[10];
  const float* b1 = (const float*)d_in[11];
  const float* W2 = (const float*)d_in[12];
  const float* b2 = (const float*)d_in[13];
  const float* Wf = (const float*)d_in[14];
  const float* bff = (const float*)d_in[15];
  const float* alpha = (const float*)d_in[16];

  char* ws = (char*)d_ws;
  size_t off = 0;
  auto alloc = [&](size_t bytes) -> void* {
    off = (off + 255) & ~(size_t)255;
    void* p = ws + off;
    off += bytes;
    return p;
  };

  bf16* wL = (bf16*)alloc(2359296L * 2);           // rotating per-layer weights (4.5 MB)
  float* bqkv = (float*)alloc(1536 * 4);
  bf16* WfB = (bf16*)alloc(512L * 512 * 2);
  bf16* wcAll = (bf16*)alloc(12L * 1024 * 512 * 2);  // folded W1R@Wm' (12 MB)
  float* bcAll = (float*)alloc(12L * 1024 * 4);      // folded bias
  float* Xf = (float*)alloc(8L * 1024 * 512 * 4);  // fp32 residual stream
  bf16* Yb = (bf16*)alloc(8L * 1024 * 1024 * 2);   // [img][n][1024]: 0:512 x, 512:1024 attnO
  bf16* QKVb = (bf16*)alloc(8L * 1024 * 1536 * 2); // [token][1536] q|k (v goes to vchan)
  bf16* vchan = (bf16*)alloc(8L * 1024 * 512 * 2); // [img][512ch][1024tok]
  char* SCR = (char*)alloc(50331648);              // 48 MB: prep tmp / T1+Zb / Ch+CTh+mproj
  float* stats = (float*)alloc(12L * 16384 * 4);   // per-layer IN stats
  u64t* u = (u64t*)alloc(4L * 1025 * 8);           // (tag<<32 | f32) pairs
  u64t* v = (u64t*)alloc(4L * 1025 * 8);

  bf16* wqkv = wL;                  // [1536][512]
  bf16* w1m = wL + 786432;          // [1024][1024] merged [W1left | Wc]
  bf16* w2 = wL + 1835008;          // [512][1024]
  float* T1 = (float*)SCR;                 // 32 MB
  bf16* Zb = (bf16*)(SCR + 33554432);      // 16 MB
  bf16* w1rTmp = (bf16*)SCR;               // prep: 12 MB (pre-layer-loop only)
  bf16* wmTTmp = (bf16*)(SCR + 12582912);  // prep: 6 MB
  __half* Ch = (__half*)SCR;               // 8.4 MB fp16 couplings (post-layers)
  __half* CTh = (__half*)(SCR + 8405248);  // 8.4 MB fp16 transposed
  bf16* mproj = (bf16*)(SCR + 33554432);   // 8 MB (post-layers)
  float* coup = (float*)d_out;

  cvt_f2b<<<512, 256, 0, stream>>>(Wf, WfB, 512L * 512);
  init_x<<<2048, 256, 0, stream>>>(descs0, descs1, Xf, Yb);
  // zero all 12 layers' stats slices once
  hipMemsetAsync(stats, 0, 12L * 16384 * 4, stream);

  auto gemm = [&](int ntile, const bf16* A, const bf16* B, int M, int N, int K,
                  int lda, int ldb, long sAimg, long sAh, long sBimg, long sBh,
                  int Z, int ZH, int cross, float scale, const float* bias,
                  float* Cf, int ldcf, long sCfImg, long sCfH,
                  bf16* Cb, int ldcb, long sCbImg, long sCbH,
                  __half* Ch_, int ldch, long sChImg, long sChH,
                  const float* resid, bf16* Cv, int vColOfs, float* statsOut) {
    GemmP p;
    p.A = A; p.B = B; p.M = M; p.N = N; p.K = K; p.lda = lda; p.ldb = ldb;
    p.sAimg = sAimg; p.sAh = sAh; p.sBimg = sBimg; p.sBh = sBh;
    p.ZH = ZH; p.cross = cross; p.scale = scale; p.bias = bias;
    p.Cf = Cf; p.ldcf = ldcf; p.sCfImg = sCfImg; p.sCfH = sCfH;
    p.Cb = Cb; p.ldcb = ldcb; p.sCbImg = sCbImg; p.sCbH = sCbH;
    p.Ch = Ch_; p.ldch = ldch; p.sChImg = sChImg; p.sChH = sChH;
    p.resid = resid; p.Cv = Cv; p.vColOfs = vColOfs; p.statsOut = statsOut;
    dim3 g((unsigned)((N + ntile - 1) / ntile), (unsigned)((M + 127) / 128), (unsigned)Z);
    if (ntile == 128) gemm_bt<128><<<g, 256, 0, stream>>>(p);
    else gemm_bt<64><<<g, 256, 0, stream>>>(p);
  };

  // ---- upfront fold: Wc[l] = W1R[l] @ wm'[l]  (batched Z=12), bc = b1 + W1R@bm ----
  cvt_prep<<<36864, 256, 0, stream>>>(W1, Wm, w1rTmp, wmTTmp);
  bc_calc<<<3072, 256, 0, stream>>>(W1, bm, b1, bcAll);
  gemm(128, w1rTmp, wmTTmp, 1024, 512, 512, 512, 512, 524288, 0, 262144, 0,
       12, 1, 0, 1.f, nullptr,
       nullptr, 0, 0, 0, wcAll, 512, 524288, 0, nullptr, 0, 0, 0,
       nullptr, nullptr, 0, nullptr);

  for (int i = 0; i < 12; i++) {
    const int cross = i & 1;  // NAMES = self,cross,self,...
    cvt_layer<<<2310, 256, 0, stream>>>(Wq, Wk, Wv, W1, W2, wcAll, bq, bk, bvv, i, wL, bqkv);

    // fused QKV: [8192,1536] = Yb[:, :512] x Wqkv^T; v-cols transposed into vchan
    gemm(128, Yb, wqkv, 8192, 1536, 512, 1024, 512, 0, 0, 0, 0, 1, 1, 0, 1.f, bqkv,
         nullptr, 0, 0, 0, QKVb, 1536, 0, 0, nullptr, 0, 0, 0,
         nullptr, vchan, 1024, nullptr);
    // fused flash attention -> Yb[:, 512:1024] (O in head-major channel order)
    attn_fused<<<dim3(16, 1, 64), 256, 0, stream>>>(QKVb, vchan, Yb, cross);

    // T1 = [W1L | Wc] x [x; O] + bc; instance-norm stats fused into epilogue
    gemm(128, Yb, w1m, 8192, 1024, 1024, 1024, 1024, 0, 0, 0, 0, 1, 1, 0, 1.f,
         bcAll + i * 1024,
         T1, 1024, 0, 0, nullptr, 0, 0, 0, nullptr, 0, 0, 0,
         nullptr, nullptr, 0, stats + (long)i * 16384);
    in_apply<<<2048, 256, 0, stream>>>(T1, stats + (long)i * 16384, Zb);
    // x += W2 z + b2 (NTILE=64: 512 blocks -> 2 blocks/CU)
    gemm(64, Zb, w2, 8192, 512, 1024, 1024, 1024, 0, 0, 0, 0, 1, 1, 0, 1.f, b2 + i * 512,
         Xf, 512, 0, 0, Yb, 1024, 0, 0, nullptr, 0, 0, 0,
         Xf, nullptr, 0, nullptr);
  }

  // final projection + score matrix into d_out
  gemm(64, Yb, WfB, 8192, 512, 512, 1024, 512, 0, 0, 0, 0, 1, 1, 0, 1.f, bff,
       nullptr, 0, 0, 0, mproj, 512, 0, 0, nullptr, 0, 0, 0,
       nullptr, nullptr, 0, nullptr);
  gemm(64, mproj, mproj + 524288, 1024, 1024, 512, 512, 512,
       1048576, 0, 1048576, 0, 4, 1, 0,
       0.044194173824159216f, nullptr,
       coup, 1025, 1050625, 0, nullptr, 0, 0, 0, nullptr, 0, 0, 0,
       nullptr, nullptr, 0, nullptr);
  coup_to_fp16<<<dim3(33, 33, 4), 256, 0, stream>>>(coup, alpha, Ch, CTh);

  hipMemsetAsync(u, 0, 4L * 1025 * 8, stream);
  hipMemsetAsync(v, 0, 4L * 1025 * 8, stream);
  const float NORM = -logf(2048.f);
  const float LOGN = logf(1024.f);
  int iters = 100;
  void* args[] = {(void*)&Ch, (void*)&CTh, (void*)&u, (void*)&v,
                  (void*)&NORM, (void*)&LOGN, (void*)&iters};
  hipLaunchCooperativeKernel((void*)sinkhorn_pers, dim3(SK_BLOCKS), dim3(1024), args, 0, stream);
  ot_final<<<16417, 256, 0, stream>>>(coup, u, v, NORM);
}